// Round 1
// baseline (1943.537 us; speedup 1.0000x reference)
//
#include <hip/hip_runtime.h>
#include <math.h>

#define NN 50000
#define EE 800000
#define GG 64
#define HH 96
#define H2 192
#define INF 32
#define EDF 16
#define OUTF 128
#define EPS_GEN 1e-7f
#define EPS_BN 1e-5f

static inline size_t align256(size_t x) { return (x + 255) & ~(size_t)255; }

// ---------------- CSR build ----------------

__global__ __launch_bounds__(256) void hist_kernel(const int* __restrict__ dst,
                                                   int* __restrict__ deg) {
    int e = blockIdx.x * 256 + threadIdx.x;
    if (e >= EE) return;
    atomicAdd(&deg[dst[e]], 1);
}

__global__ __launch_bounds__(1024) void scan_kernel(const int* __restrict__ deg,
                                                    int* __restrict__ offs, int n) {
    __shared__ int wsum[16];
    __shared__ int carry_s;
    int tid = threadIdx.x, lane = tid & 63, w = tid >> 6;
    if (tid == 0) carry_s = 0;
    __syncthreads();
    for (int base = 0; base < n; base += 1024) {
        int i = base + tid;
        int v = (i < n) ? deg[i] : 0;
        int x = v;
        #pragma unroll
        for (int off = 1; off < 64; off <<= 1) {
            int y = __shfl_up(x, off, 64);
            if (lane >= off) x += y;
        }
        if (lane == 63) wsum[w] = x;
        __syncthreads();
        int wpre = 0;
        for (int j = 0; j < w; ++j) wpre += wsum[j];
        int carry = carry_s;
        if (i < n) offs[i] = carry + wpre + x - v;  // exclusive prefix
        __syncthreads();
        if (tid == 1023) carry_s = carry + wpre + x;
        __syncthreads();
    }
    if (threadIdx.x == 0) offs[n] = carry_s;
}

__global__ __launch_bounds__(256) void scatter_kernel(const int* __restrict__ src,
                                                      const int* __restrict__ dst,
                                                      const int* __restrict__ offs,
                                                      int* __restrict__ cnt2,
                                                      int* __restrict__ csr_src,
                                                      int* __restrict__ csr_eid) {
    int e = blockIdx.x * 256 + threadIdx.x;
    if (e >= EE) return;
    int d = dst[e];
    int slot = offs[d] + atomicAdd(&cnt2[d], 1);
    csr_src[slot] = src[e];
    csr_eid[slot] = e;
}

// ---------------- layer-1 input projections ----------------

__global__ __launch_bounds__(256) void proj_kernel(const float* __restrict__ x,
                                                   const float* __restrict__ ws,
                                                   const float* __restrict__ wd,
                                                   float* __restrict__ xs,
                                                   float* __restrict__ xd) {
    __shared__ float Ws[INF * HH], Wd[INF * HH];
    int tid = threadIdx.x;
    for (int i = tid; i < INF * HH; i += 256) { Ws[i] = ws[i]; Wd[i] = wd[i]; }
    __syncthreads();
    int gid = blockIdx.x * 256 + tid;
    if (gid >= NN * HH) return;
    int n = gid / HH, c = gid % HH;
    const float* xr = x + (size_t)n * INF;
    float as = 0.f, ad = 0.f;
    #pragma unroll
    for (int k = 0; k < INF; ++k) {
        float xv = xr[k];
        as = fmaf(xv, Ws[k * HH + c], as);
        ad = fmaf(xv, Wd[k * HH + c], ad);
    }
    xs[gid] = as;
    xd[gid] = ad;
}

// ---------------- GENConv softmax aggregation (online, single pass) ----------------

__global__ __launch_bounds__(192) void agg_kernel(const float* __restrict__ xsrc,
                                                  const float* __restrict__ xdst,
                                                  const float* __restrict__ eattr,
                                                  const float* __restrict__ w_edge,
                                                  const int* __restrict__ offs,
                                                  const int* __restrict__ csr_src,
                                                  const int* __restrict__ csr_eid,
                                                  float* __restrict__ hpre) {
    int node = blockIdx.x * 2 + (threadIdx.x / HH);
    int c = threadIdx.x % HH;
    if (node >= NN) return;
    float wc[EDF];
    #pragma unroll
    for (int k = 0; k < EDF; ++k) wc[k] = w_edge[k * HH + c];
    int s0 = offs[node], s1 = offs[node + 1];
    float m = -3.4e38f, num = 0.f, den = 0.f;
    for (int j = s0; j < s1; ++j) {
        int sn = csr_src[j];
        int eid = csr_eid[j];
        const float* ea = eattr + (size_t)eid * EDF;
        float acc = 0.f;
        #pragma unroll
        for (int k = 0; k < EDF; ++k) acc = fmaf(ea[k], wc[k], acc);
        float xv = xsrc[(size_t)sn * HH + c];
        float msg = fmaxf(xv + acc, 0.f) + EPS_GEN;
        if (msg > m) {
            float sc = __expf(m - msg);  // first iter: exp(-huge)=0 zeroes num/den
            num *= sc; den *= sc; m = msg;
        }
        float p = __expf(msg - m);
        den += p;
        num = fmaf(msg, p, num);
    }
    float agg = (den > 0.f) ? (num / den) : 0.f;
    hpre[(size_t)node * HH + c] = agg + xdst[(size_t)node * HH + c];
}

// ---------------- t = hpre @ mw1  [N,96]x[96,192], + column stats ----------------

__global__ __launch_bounds__(192) void gemm1_kernel(const float* __restrict__ A,
                                                    const float* __restrict__ W,
                                                    float* __restrict__ T,
                                                    float* __restrict__ colsum,
                                                    float* __restrict__ colsumsq) {
    __shared__ float As[32 * HH];
    int n0 = blockIdx.x * 32;
    int tid = threadIdx.x;
    for (int i = tid; i < 32 * HH; i += 192) {
        int n = i / HH;
        As[i] = (n0 + n < NN) ? A[(size_t)(n0 + n) * HH + (i % HH)] : 0.f;
    }
    __syncthreads();
    int c = tid;  // 0..191
    float acc[32];
    #pragma unroll
    for (int n = 0; n < 32; ++n) acc[n] = 0.f;
    for (int k = 0; k < HH; k += 4) {
        float b0 = W[(k + 0) * H2 + c];
        float b1 = W[(k + 1) * H2 + c];
        float b2 = W[(k + 2) * H2 + c];
        float b3 = W[(k + 3) * H2 + c];
        #pragma unroll
        for (int n = 0; n < 32; ++n) {
            const float4 a4 = *reinterpret_cast<const float4*>(&As[n * HH + k]);
            acc[n] = fmaf(a4.x, b0, fmaf(a4.y, b1, fmaf(a4.z, b2, fmaf(a4.w, b3, acc[n]))));
        }
    }
    float s = 0.f, ss = 0.f;
    for (int n = 0; n < 32; ++n) {
        if (n0 + n < NN) {
            float v = acc[n];
            T[(size_t)(n0 + n) * H2 + c] = v;
            s += v;
            ss = fmaf(v, v, ss);
        }
    }
    atomicAdd(&colsum[c], s);
    atomicAdd(&colsumsq[c], ss);
}

// ---------------- finalize BN affine:  a=g*rsqrt(var+eps), b'=b-mu*a ----------------

__global__ __launch_bounds__(256) void finalize_bn(const float* __restrict__ colsum,
                                                   const float* __restrict__ colsumsq,
                                                   const float* __restrict__ g,
                                                   const float* __restrict__ b,
                                                   float* __restrict__ a_out,
                                                   float* __restrict__ b_out, int C) {
    int c = threadIdx.x;
    if (c >= C) return;
    const float invN = 1.f / (float)NN;
    float mu = colsum[c] * invN;
    float var = fmaxf(colsumsq[c] * invN - mu * mu, 0.f);
    float a = g[c] * rsqrtf(var + EPS_BN);
    a_out[c] = a;
    b_out[c] = b[c] - mu * a;
}

// ------- u = relu(bn_in(t)) @ mw2  [N,192]x[192,96], + column stats -------

__global__ __launch_bounds__(192) void gemm2_kernel(const float* __restrict__ T,
                                                    const float* __restrict__ W,
                                                    const float* __restrict__ a1,
                                                    const float* __restrict__ b1,
                                                    float* __restrict__ U,
                                                    float* __restrict__ colsum,
                                                    float* __restrict__ colsumsq) {
    __shared__ float As[64 * H2];  // 48 KiB
    int n0 = blockIdx.x * 64;
    int tid = threadIdx.x;
    for (int i = tid; i < 64 * H2; i += 192) {
        int n = i / H2, k = i % H2;
        float v = 0.f;
        if (n0 + n < NN) v = fmaxf(fmaf(T[(size_t)(n0 + n) * H2 + k], a1[k], b1[k]), 0.f);
        As[i] = v;
    }
    __syncthreads();
    int c = tid % HH, h = tid / HH;  // h in {0,1}
    float acc[32];
    #pragma unroll
    for (int n = 0; n < 32; ++n) acc[n] = 0.f;
    for (int k = 0; k < H2; k += 4) {
        float b0 = W[(k + 0) * HH + c];
        float b1w = W[(k + 1) * HH + c];
        float b2 = W[(k + 2) * HH + c];
        float b3 = W[(k + 3) * HH + c];
        #pragma unroll
        for (int n = 0; n < 32; ++n) {
            const float4 a4 = *reinterpret_cast<const float4*>(&As[(h * 32 + n) * H2 + k]);
            acc[n] = fmaf(a4.x, b0, fmaf(a4.y, b1w, fmaf(a4.z, b2, fmaf(a4.w, b3, acc[n]))));
        }
    }
    float s = 0.f, ss = 0.f;
    for (int n = 0; n < 32; ++n) {
        int nn = n0 + h * 32 + n;
        if (nn < NN) {
            float v = acc[n];
            U[(size_t)nn * HH + c] = v;
            s += v;
            ss = fmaf(v, v, ss);
        }
    }
    atomicAdd(&colsum[c], s);
    atomicAdd(&colsumsq[c], ss);
}

// ---------------- h = relu(bn_out(u)) ----------------

__global__ __launch_bounds__(256) void elem_kernel(const float* __restrict__ U,
                                                   const float* __restrict__ a2,
                                                   const float* __restrict__ b2,
                                                   float* __restrict__ Hout) {
    int i = blockIdx.x * 256 + threadIdx.x;
    if (i >= NN * HH) return;
    int c = i % HH;
    Hout[i] = fmaxf(fmaf(U[i], a2[c], b2[c]), 0.f);
}

// ---------------- mean-pool ----------------

__global__ __launch_bounds__(256) void pool_kernel(const float* __restrict__ Hfin,
                                                   const int* __restrict__ batch,
                                                   float* __restrict__ pool,
                                                   float* __restrict__ pcnt) {
    int i = blockIdx.x * 256 + threadIdx.x;
    if (i >= NN * HH) return;
    int n = i / HH, c = i % HH;
    int g = batch[n];
    atomicAdd(&pool[(size_t)g * HH + c], Hfin[i]);
    if (c == 0) atomicAdd(&pcnt[g], 1.f);
}

__global__ __launch_bounds__(128) void out_kernel(const float* __restrict__ pool,
                                                  const float* __restrict__ pcnt,
                                                  const float* __restrict__ lw,
                                                  const float* __restrict__ lb,
                                                  float* __restrict__ out) {
    int g = blockIdx.x, o = threadIdx.x;
    float inv = 1.f / fmaxf(pcnt[g], 1.f);
    float acc = lb[o];
    for (int c = 0; c < HH; ++c) acc = fmaf(pool[g * HH + c] * inv, lw[c * OUTF + o], acc);
    out[(size_t)g * OUTF + o] = acc;
}

// ---------------- host ----------------

extern "C" void kernel_launch(void* const* d_in, const int* in_sizes, int n_in,
                              void* d_out, int out_size, void* d_ws, size_t ws_size,
                              hipStream_t stream) {
    const float* x = (const float*)d_in[0];
    const float* eattr = (const float*)d_in[1];
    const int* eidx = (const int*)d_in[2];
    const int* batch = (const int*)d_in[3];
    const float* w_src1 = (const float*)d_in[4];
    const float* w_dst1 = (const float*)d_in[5];
    const float* w_e[3] = {(const float*)d_in[6], (const float*)d_in[13], (const float*)d_in[20]};
    const float* mw1[3] = {(const float*)d_in[7], (const float*)d_in[14], (const float*)d_in[21]};
    const float* mg[3] = {(const float*)d_in[8], (const float*)d_in[15], (const float*)d_in[22]};
    const float* mb[3] = {(const float*)d_in[9], (const float*)d_in[16], (const float*)d_in[23]};
    const float* mw2[3] = {(const float*)d_in[10], (const float*)d_in[17], (const float*)d_in[24]};
    const float* bng[3] = {(const float*)d_in[11], (const float*)d_in[18], (const float*)d_in[25]};
    const float* bnb[3] = {(const float*)d_in[12], (const float*)d_in[19], (const float*)d_in[26]};
    const float* lin_w = (const float*)d_in[27];
    const float* lin_b = (const float*)d_in[28];
    float* out = (float*)d_out;

    const int* src = eidx;        // edge_index row 0
    const int* dst = eidx + EE;   // edge_index row 1

    // ---- workspace layout ----
    char* base = (char*)d_ws;
    size_t off = 0;
    int* deg = (int*)(base + off); off = align256(off + (size_t)NN * 4);
    int* cnt2 = (int*)(base + off); off = align256(off + (size_t)NN * 4);
    int* offs = (int*)(base + off); off = align256(off + (size_t)(NN + 1) * 4);
    int* csr_src = (int*)(base + off); off = align256(off + (size_t)EE * 4);
    int* csr_eid = (int*)(base + off); off = align256(off + (size_t)EE * 4);
    float* stats = (float*)(base + off); off = align256(off + 1152 * 4);
    float* colsum1 = stats;            // 192
    float* colsumsq1 = stats + 192;    // 192
    float* colsum2 = stats + 384;      // 96
    float* colsumsq2 = stats + 480;    // 96  (first 576 floats zeroed per layer)
    float* a1 = stats + 576;           // 192
    float* b1 = stats + 768;           // 192
    float* a2 = stats + 960;           // 96
    float* b2 = stats + 1056;          // 96
    float* pool = (float*)(base + off); off = align256(off + (size_t)GG * HH * 4);
    float* pcnt = (float*)(base + off); off = align256(off + (size_t)GG * 4);
    float* A = (float*)(base + off); off = align256(off + (size_t)NN * HH * 4);  // xs -> h
    float* B = (float*)(base + off); off = align256(off + (size_t)NN * HH * 4);  // hpre -> u
    float* C = (float*)(base + off); off = align256(off + (size_t)NN * H2 * 4);  // xd -> t
    (void)ws_size; (void)in_sizes; (void)n_in; (void)out_size;

    // ---- CSR build ----
    hipMemsetAsync(deg, 0, (size_t)NN * 4, stream);
    hipMemsetAsync(cnt2, 0, (size_t)NN * 4, stream);
    hist_kernel<<<(EE + 255) / 256, 256, 0, stream>>>(dst, deg);
    scan_kernel<<<1, 1024, 0, stream>>>(deg, offs, NN);
    scatter_kernel<<<(EE + 255) / 256, 256, 0, stream>>>(src, dst, offs, cnt2, csr_src, csr_eid);

    // ---- layer-1 projections ----
    proj_kernel<<<(NN * HH + 255) / 256, 256, 0, stream>>>(x, w_src1, w_dst1, A, C);

    // ---- 3 GENConv layers ----
    for (int l = 0; l < 3; ++l) {
        const float* xsrc = A;
        const float* xdst = (l == 0) ? C : A;
        hipMemsetAsync(stats, 0, 576 * 4, stream);
        agg_kernel<<<NN / 2, 192, 0, stream>>>(xsrc, xdst, eattr, w_e[l], offs, csr_src,
                                               csr_eid, B);
        gemm1_kernel<<<(NN + 31) / 32, 192, 0, stream>>>(B, mw1[l], C, colsum1, colsumsq1);
        finalize_bn<<<1, 256, 0, stream>>>(colsum1, colsumsq1, mg[l], mb[l], a1, b1, H2);
        gemm2_kernel<<<(NN + 63) / 64, 192, 0, stream>>>(C, mw2[l], a1, b1, B, colsum2,
                                                         colsumsq2);
        finalize_bn<<<1, 256, 0, stream>>>(colsum2, colsumsq2, bng[l], bnb[l], a2, b2, HH);
        elem_kernel<<<(NN * HH + 255) / 256, 256, 0, stream>>>(B, a2, b2, A);
    }

    // ---- pooling + final linear ----
    hipMemsetAsync(pool, 0, (size_t)(GG * HH) * 4, stream);
    hipMemsetAsync(pcnt, 0, (size_t)GG * 4, stream);
    pool_kernel<<<(NN * HH + 255) / 256, 256, 0, stream>>>(A, batch, pool, pcnt);
    out_kernel<<<GG, 128, 0, stream>>>(pool, pcnt, lin_w, lin_b, out);
}

// Round 2
// 1564.610 us; speedup vs baseline: 1.2422x; 1.2422x over previous
//
#include <hip/hip_runtime.h>
#include <math.h>

#define NN 50000
#define EE 800000
#define GG 64
#define HH 96
#define H2 192
#define INF 32
#define EDF 16
#define OUTF 128
#define EPS_GEN 1e-7f
#define EPS_BN 1e-5f
#define NPB 100  // nodes per pool block

static inline size_t align256(size_t x) { return (x + 255) & ~(size_t)255; }

// ---------------- CSR build ----------------

__global__ __launch_bounds__(256) void hist_kernel(const int* __restrict__ dst,
                                                   int* __restrict__ deg) {
    int e = blockIdx.x * 256 + threadIdx.x;
    if (e >= EE) return;
    atomicAdd(&deg[dst[e]], 1);
}

__global__ __launch_bounds__(1024) void scan_kernel(const int* __restrict__ deg,
                                                    int* __restrict__ offs, int n) {
    __shared__ int wsum[16];
    __shared__ int carry_s;
    int tid = threadIdx.x, lane = tid & 63, w = tid >> 6;
    if (tid == 0) carry_s = 0;
    __syncthreads();
    for (int base = 0; base < n; base += 1024) {
        int i = base + tid;
        int v = (i < n) ? deg[i] : 0;
        int x = v;
        #pragma unroll
        for (int off = 1; off < 64; off <<= 1) {
            int y = __shfl_up(x, off, 64);
            if (lane >= off) x += y;
        }
        if (lane == 63) wsum[w] = x;
        __syncthreads();
        int wpre = 0;
        for (int j = 0; j < w; ++j) wpre += wsum[j];
        int carry = carry_s;
        if (i < n) offs[i] = carry + wpre + x - v;  // exclusive prefix
        __syncthreads();
        if (tid == 1023) carry_s = carry + wpre + x;
        __syncthreads();
    }
    if (threadIdx.x == 0) offs[n] = carry_s;
}

__global__ __launch_bounds__(256) void scatter_kernel(const int* __restrict__ src,
                                                      const int* __restrict__ dst,
                                                      const int* __restrict__ offs,
                                                      int* __restrict__ cnt2,
                                                      int* __restrict__ csr_src,
                                                      int* __restrict__ csr_eid) {
    int e = blockIdx.x * 256 + threadIdx.x;
    if (e >= EE) return;
    int d = dst[e];
    int slot = offs[d] + atomicAdd(&cnt2[d], 1);
    csr_src[slot] = src[e];
    csr_eid[slot] = e;
}

// ---------------- layer-1 input projections ----------------

__global__ __launch_bounds__(256) void proj_kernel(const float* __restrict__ x,
                                                   const float* __restrict__ ws,
                                                   const float* __restrict__ wd,
                                                   float* __restrict__ xs,
                                                   float* __restrict__ xd) {
    __shared__ float Ws[INF * HH], Wd[INF * HH];
    int tid = threadIdx.x;
    for (int i = tid; i < INF * HH; i += 256) { Ws[i] = ws[i]; Wd[i] = wd[i]; }
    __syncthreads();
    int gid = blockIdx.x * 256 + tid;
    if (gid >= NN * HH) return;
    int n = gid / HH, c = gid % HH;
    const float* xr = x + (size_t)n * INF;
    float as = 0.f, ad = 0.f;
    #pragma unroll
    for (int k = 0; k < INF; ++k) {
        float xv = xr[k];
        as = fmaf(xv, Ws[k * HH + c], as);
        ad = fmaf(xv, Wd[k * HH + c], ad);
    }
    xs[gid] = as;
    xd[gid] = ad;
}

// ---------------- GENConv softmax aggregation (online, single pass) ----------------

__global__ __launch_bounds__(192) void agg_kernel(const float* __restrict__ xsrc,
                                                  const float* __restrict__ xdst,
                                                  const float* __restrict__ eattr,
                                                  const float* __restrict__ w_edge,
                                                  const int* __restrict__ offs,
                                                  const int* __restrict__ csr_src,
                                                  const int* __restrict__ csr_eid,
                                                  float* __restrict__ hpre) {
    int node = blockIdx.x * 2 + (threadIdx.x / HH);
    int c = threadIdx.x % HH;
    if (node >= NN) return;
    float wc[EDF];
    #pragma unroll
    for (int k = 0; k < EDF; ++k) wc[k] = w_edge[k * HH + c];
    int s0 = offs[node], s1 = offs[node + 1];
    float m = -3.4e38f, num = 0.f, den = 0.f;
    for (int j = s0; j < s1; ++j) {
        int sn = csr_src[j];
        int eid = csr_eid[j];
        const float* ea = eattr + (size_t)eid * EDF;
        float acc = 0.f;
        #pragma unroll
        for (int k = 0; k < EDF; ++k) acc = fmaf(ea[k], wc[k], acc);
        float xv = xsrc[(size_t)sn * HH + c];
        float msg = fmaxf(xv + acc, 0.f) + EPS_GEN;
        if (msg > m) {
            float sc = __expf(m - msg);  // first iter: exp(-huge)=0 zeroes num/den
            num *= sc; den *= sc; m = msg;
        }
        float p = __expf(msg - m);
        den += p;
        num = fmaf(msg, p, num);
    }
    float agg = (den > 0.f) ? (num / den) : 0.f;
    hpre[(size_t)node * HH + c] = agg + xdst[(size_t)node * HH + c];
}

// ---------------- t = hpre @ mw1  [N,96]x[96,192], + column stats ----------------

__global__ __launch_bounds__(192) void gemm1_kernel(const float* __restrict__ A,
                                                    const float* __restrict__ W,
                                                    float* __restrict__ T,
                                                    float* __restrict__ colsum,
                                                    float* __restrict__ colsumsq) {
    __shared__ float As[32 * HH];
    int n0 = blockIdx.x * 32;
    int tid = threadIdx.x;
    for (int i = tid; i < 32 * HH; i += 192) {
        int n = i / HH;
        As[i] = (n0 + n < NN) ? A[(size_t)(n0 + n) * HH + (i % HH)] : 0.f;
    }
    __syncthreads();
    int c = tid;  // 0..191
    float acc[32];
    #pragma unroll
    for (int n = 0; n < 32; ++n) acc[n] = 0.f;
    for (int k = 0; k < HH; k += 4) {
        float b0 = W[(k + 0) * H2 + c];
        float b1 = W[(k + 1) * H2 + c];
        float b2 = W[(k + 2) * H2 + c];
        float b3 = W[(k + 3) * H2 + c];
        #pragma unroll
        for (int n = 0; n < 32; ++n) {
            const float4 a4 = *reinterpret_cast<const float4*>(&As[n * HH + k]);
            acc[n] = fmaf(a4.x, b0, fmaf(a4.y, b1, fmaf(a4.z, b2, fmaf(a4.w, b3, acc[n]))));
        }
    }
    float s = 0.f, ss = 0.f;
    for (int n = 0; n < 32; ++n) {
        if (n0 + n < NN) {
            float v = acc[n];
            T[(size_t)(n0 + n) * H2 + c] = v;
            s += v;
            ss = fmaf(v, v, ss);
        }
    }
    atomicAdd(&colsum[c], s);
    atomicAdd(&colsumsq[c], ss);
}

// ---------------- finalize BN affine:  a=g*rsqrt(var+eps), b'=b-mu*a ----------------

__global__ __launch_bounds__(256) void finalize_bn(const float* __restrict__ colsum,
                                                   const float* __restrict__ colsumsq,
                                                   const float* __restrict__ g,
                                                   const float* __restrict__ b,
                                                   float* __restrict__ a_out,
                                                   float* __restrict__ b_out, int C) {
    int c = threadIdx.x;
    if (c >= C) return;
    const float invN = 1.f / (float)NN;
    float mu = colsum[c] * invN;
    float var = fmaxf(colsumsq[c] * invN - mu * mu, 0.f);
    float a = g[c] * rsqrtf(var + EPS_BN);
    a_out[c] = a;
    b_out[c] = b[c] - mu * a;
}

// ------- u = relu(bn_in(t)) @ mw2  [N,192]x[192,96], + column stats -------

__global__ __launch_bounds__(192) void gemm2_kernel(const float* __restrict__ T,
                                                    const float* __restrict__ W,
                                                    const float* __restrict__ a1,
                                                    const float* __restrict__ b1,
                                                    float* __restrict__ U,
                                                    float* __restrict__ colsum,
                                                    float* __restrict__ colsumsq) {
    __shared__ float As[64 * H2];  // 48 KiB
    int n0 = blockIdx.x * 64;
    int tid = threadIdx.x;
    for (int i = tid; i < 64 * H2; i += 192) {
        int n = i / H2, k = i % H2;
        float v = 0.f;
        if (n0 + n < NN) v = fmaxf(fmaf(T[(size_t)(n0 + n) * H2 + k], a1[k], b1[k]), 0.f);
        As[i] = v;
    }
    __syncthreads();
    int c = tid % HH, h = tid / HH;  // h in {0,1}
    float acc[32];
    #pragma unroll
    for (int n = 0; n < 32; ++n) acc[n] = 0.f;
    for (int k = 0; k < H2; k += 4) {
        float b0 = W[(k + 0) * HH + c];
        float b1w = W[(k + 1) * HH + c];
        float b2 = W[(k + 2) * HH + c];
        float b3 = W[(k + 3) * HH + c];
        #pragma unroll
        for (int n = 0; n < 32; ++n) {
            const float4 a4 = *reinterpret_cast<const float4*>(&As[(h * 32 + n) * H2 + k]);
            acc[n] = fmaf(a4.x, b0, fmaf(a4.y, b1w, fmaf(a4.z, b2, fmaf(a4.w, b3, acc[n]))));
        }
    }
    float s = 0.f, ss = 0.f;
    for (int n = 0; n < 32; ++n) {
        int nn = n0 + h * 32 + n;
        if (nn < NN) {
            float v = acc[n];
            U[(size_t)nn * HH + c] = v;
            s += v;
            ss = fmaf(v, v, ss);
        }
    }
    atomicAdd(&colsum[c], s);
    atomicAdd(&colsumsq[c], ss);
}

// ---------------- h = relu(bn_out(u)) ----------------

__global__ __launch_bounds__(256) void elem_kernel(const float* __restrict__ U,
                                                   const float* __restrict__ a2,
                                                   const float* __restrict__ b2,
                                                   float* __restrict__ Hout) {
    int i = blockIdx.x * 256 + threadIdx.x;
    if (i >= NN * HH) return;
    int c = i % HH;
    Hout[i] = fmaxf(fmaf(U[i], a2[c], b2[c]), 0.f);
}

// ---------------- mean-pool: segmented register accumulation ----------------
// batch is sorted; each block owns NPB consecutive nodes, each thread one
// channel (x2 node-interleave). Running per-graph partial sum in a register,
// one atomic per graph-transition per thread (~25 atomics/address total,
// vs ~781 serialized adds/address in the naive version).

__global__ __launch_bounds__(192) void pool_kernel(const float* __restrict__ Hfin,
                                                   const int* __restrict__ batch,
                                                   float* __restrict__ pool) {
    int n0 = blockIdx.x * NPB;
    int n1 = (n0 + NPB < NN) ? n0 + NPB : NN;
    int c = threadIdx.x % HH;
    int h = threadIdx.x / HH;  // 0 or 1
    float acc = 0.f;
    int gcur = -1;
    for (int n = n0 + h; n < n1; n += 2) {
        int g = batch[n];  // wave-broadcast load
        if (g != gcur) {
            if (gcur >= 0) atomicAdd(&pool[(size_t)gcur * HH + c], acc);
            acc = 0.f;
            gcur = g;
        }
        acc += Hfin[(size_t)n * HH + c];
    }
    if (gcur >= 0) atomicAdd(&pool[(size_t)gcur * HH + c], acc);
}

// counts per graph via binary search on sorted batch (no atomics)
__global__ __launch_bounds__(64) void cnt_kernel(const int* __restrict__ batch,
                                                 float* __restrict__ pcnt) {
    int g = threadIdx.x;
    if (g >= GG) return;
    int lo = 0, hi = NN;
    while (lo < hi) { int mid = (lo + hi) >> 1; if (batch[mid] < g) lo = mid + 1; else hi = mid; }
    int s = lo;
    lo = 0; hi = NN;
    while (lo < hi) { int mid = (lo + hi) >> 1; if (batch[mid] < g + 1) lo = mid + 1; else hi = mid; }
    pcnt[g] = (float)(lo - s);
}

__global__ __launch_bounds__(128) void out_kernel(const float* __restrict__ pool,
                                                  const float* __restrict__ pcnt,
                                                  const float* __restrict__ lw,
                                                  const float* __restrict__ lb,
                                                  float* __restrict__ out) {
    int g = blockIdx.x, o = threadIdx.x;
    float inv = 1.f / fmaxf(pcnt[g], 1.f);
    float acc = lb[o];
    for (int c = 0; c < HH; ++c) acc = fmaf(pool[g * HH + c] * inv, lw[c * OUTF + o], acc);
    out[(size_t)g * OUTF + o] = acc;
}

// ---------------- host ----------------

extern "C" void kernel_launch(void* const* d_in, const int* in_sizes, int n_in,
                              void* d_out, int out_size, void* d_ws, size_t ws_size,
                              hipStream_t stream) {
    const float* x = (const float*)d_in[0];
    const float* eattr = (const float*)d_in[1];
    const int* eidx = (const int*)d_in[2];
    const int* batch = (const int*)d_in[3];
    const float* w_src1 = (const float*)d_in[4];
    const float* w_dst1 = (const float*)d_in[5];
    const float* w_e[3] = {(const float*)d_in[6], (const float*)d_in[13], (const float*)d_in[20]};
    const float* mw1[3] = {(const float*)d_in[7], (const float*)d_in[14], (const float*)d_in[21]};
    const float* mg[3] = {(const float*)d_in[8], (const float*)d_in[15], (const float*)d_in[22]};
    const float* mb[3] = {(const float*)d_in[9], (const float*)d_in[16], (const float*)d_in[23]};
    const float* mw2[3] = {(const float*)d_in[10], (const float*)d_in[17], (const float*)d_in[24]};
    const float* bng[3] = {(const float*)d_in[11], (const float*)d_in[18], (const float*)d_in[25]};
    const float* bnb[3] = {(const float*)d_in[12], (const float*)d_in[19], (const float*)d_in[26]};
    const float* lin_w = (const float*)d_in[27];
    const float* lin_b = (const float*)d_in[28];
    float* out = (float*)d_out;

    const int* src = eidx;        // edge_index row 0
    const int* dst = eidx + EE;   // edge_index row 1

    // ---- workspace layout ----
    char* base = (char*)d_ws;
    size_t off = 0;
    int* deg = (int*)(base + off); off = align256(off + (size_t)NN * 4);
    int* cnt2 = (int*)(base + off); off = align256(off + (size_t)NN * 4);
    int* offs = (int*)(base + off); off = align256(off + (size_t)(NN + 1) * 4);
    int* csr_src = (int*)(base + off); off = align256(off + (size_t)EE * 4);
    int* csr_eid = (int*)(base + off); off = align256(off + (size_t)EE * 4);
    float* stats = (float*)(base + off); off = align256(off + 1152 * 4);
    float* colsum1 = stats;            // 192
    float* colsumsq1 = stats + 192;    // 192
    float* colsum2 = stats + 384;      // 96
    float* colsumsq2 = stats + 480;    // 96  (first 576 floats zeroed per layer)
    float* a1 = stats + 576;           // 192
    float* b1 = stats + 768;           // 192
    float* a2 = stats + 960;           // 96
    float* b2 = stats + 1056;          // 96
    float* pool = (float*)(base + off); off = align256(off + (size_t)GG * HH * 4);
    float* pcnt = (float*)(base + off); off = align256(off + (size_t)GG * 4);
    float* A = (float*)(base + off); off = align256(off + (size_t)NN * HH * 4);  // xs -> h
    float* B = (float*)(base + off); off = align256(off + (size_t)NN * HH * 4);  // hpre -> u
    float* C = (float*)(base + off); off = align256(off + (size_t)NN * H2 * 4);  // xd -> t
    (void)ws_size; (void)in_sizes; (void)n_in; (void)out_size;

    // ---- CSR build ----
    hipMemsetAsync(deg, 0, (size_t)NN * 4, stream);
    hipMemsetAsync(cnt2, 0, (size_t)NN * 4, stream);
    hist_kernel<<<(EE + 255) / 256, 256, 0, stream>>>(dst, deg);
    scan_kernel<<<1, 1024, 0, stream>>>(deg, offs, NN);
    scatter_kernel<<<(EE + 255) / 256, 256, 0, stream>>>(src, dst, offs, cnt2, csr_src, csr_eid);

    // ---- layer-1 projections ----
    proj_kernel<<<(NN * HH + 255) / 256, 256, 0, stream>>>(x, w_src1, w_dst1, A, C);

    // ---- 3 GENConv layers ----
    for (int l = 0; l < 3; ++l) {
        const float* xsrc = A;
        const float* xdst = (l == 0) ? C : A;
        hipMemsetAsync(stats, 0, 576 * 4, stream);
        agg_kernel<<<NN / 2, 192, 0, stream>>>(xsrc, xdst, eattr, w_e[l], offs, csr_src,
                                               csr_eid, B);
        gemm1_kernel<<<(NN + 31) / 32, 192, 0, stream>>>(B, mw1[l], C, colsum1, colsumsq1);
        finalize_bn<<<1, 256, 0, stream>>>(colsum1, colsumsq1, mg[l], mb[l], a1, b1, H2);
        gemm2_kernel<<<(NN + 63) / 64, 192, 0, stream>>>(C, mw2[l], a1, b1, B, colsum2,
                                                         colsumsq2);
        finalize_bn<<<1, 256, 0, stream>>>(colsum2, colsumsq2, bng[l], bnb[l], a2, b2, HH);
        elem_kernel<<<(NN * HH + 255) / 256, 256, 0, stream>>>(B, a2, b2, A);
    }

    // ---- pooling + final linear ----
    hipMemsetAsync(pool, 0, (size_t)(GG * HH) * 4, stream);
    pool_kernel<<<(NN + NPB - 1) / NPB, 192, 0, stream>>>(A, batch, pool);
    cnt_kernel<<<1, 64, 0, stream>>>(batch, pcnt);
    out_kernel<<<GG, 128, 0, stream>>>(pool, pcnt, lin_w, lin_b, out);
}

// Round 3
// 977.089 us; speedup vs baseline: 1.9891x; 1.6013x over previous
//
#include <hip/hip_runtime.h>
#include <math.h>

#define NN 50000
#define EE 800000
#define GG 64
#define HH 96
#define H2 192
#define INF 32
#define EDF 16
#define OUTF 128
#define EPS_GEN 1e-7f
#define EPS_BN 1e-5f
#define NPB 100   // nodes per pool block
#define NB_SCAN 49  // ceil(NN/1024)

typedef _Float16 f16x2 __attribute__((ext_vector_type(2)));

static inline size_t align256(size_t x) { return (x + 255) & ~(size_t)255; }

__device__ __forceinline__ float fdot2(f16x2 a, f16x2 b, float c) {
#if __has_builtin(__builtin_amdgcn_fdot2)
    return __builtin_amdgcn_fdot2(a, b, c, false);
#else
    return fmaf((float)a.x, (float)b.x, fmaf((float)a.y, (float)b.y, c));
#endif
}

// ---------------- CSR build ----------------

__global__ __launch_bounds__(256) void hist_kernel(const int* __restrict__ dst,
                                                   int* __restrict__ deg) {
    int e = blockIdx.x * 256 + threadIdx.x;
    if (e >= EE) return;
    atomicAdd(&deg[dst[e]], 1);
}

// block-local exclusive scan + per-block totals
__global__ __launch_bounds__(1024) void scan1_kernel(const int* __restrict__ deg,
                                                     int* __restrict__ offs,
                                                     int* __restrict__ bsum) {
    __shared__ int ws[16];
    int tid = threadIdx.x, lane = tid & 63, w = tid >> 6;
    int i = blockIdx.x * 1024 + tid;
    int v = (i < NN) ? deg[i] : 0;
    int x = v;
    #pragma unroll
    for (int off = 1; off < 64; off <<= 1) {
        int y = __shfl_up(x, off, 64);
        if (lane >= off) x += y;
    }
    if (lane == 63) ws[w] = x;
    __syncthreads();
    int wpre = 0;
    for (int j = 0; j < w; ++j) wpre += ws[j];
    if (i < NN) offs[i] = wpre + x - v;  // block-local exclusive
    if (tid == 1023) bsum[blockIdx.x] = wpre + x;
}

__global__ __launch_bounds__(64) void scan2_kernel(int* __restrict__ bsum) {
    int lane = threadIdx.x;
    int v = (lane < NB_SCAN) ? bsum[lane] : 0;
    int x = v;
    #pragma unroll
    for (int off = 1; off < 64; off <<= 1) {
        int y = __shfl_up(x, off, 64);
        if (lane >= off) x += y;
    }
    if (lane < NB_SCAN) bsum[lane] = x - v;  // exclusive
}

__global__ __launch_bounds__(256) void scan3_kernel(int* __restrict__ offs,
                                                    const int* __restrict__ bsum) {
    int i = blockIdx.x * 256 + threadIdx.x;
    if (i < NN) offs[i] += bsum[i >> 10];
    if (i == 0) offs[NN] = EE;
}

__global__ __launch_bounds__(256) void scatter_kernel(const int* __restrict__ src,
                                                      const int* __restrict__ dst,
                                                      const int* __restrict__ offs,
                                                      int* __restrict__ cnt2,
                                                      int* __restrict__ csr_src,
                                                      int* __restrict__ csr_eid) {
    int e = blockIdx.x * 256 + threadIdx.x;
    if (e >= EE) return;
    int d = dst[e];
    int slot = offs[d] + atomicAdd(&cnt2[d], 1);
    csr_src[slot] = src[e];
    csr_eid[slot] = e;
}

// gather edge attrs into CSR order, converted to f16 (32 B/slot, sequential reads in agg)
__global__ __launch_bounds__(256) void csrcvt_kernel(const int* __restrict__ csr_eid,
                                                     const float* __restrict__ eattr,
                                                     float4* __restrict__ csrea) {
    int j = blockIdx.x * 256 + threadIdx.x;
    if (j >= EE) return;
    int eid = csr_eid[j];
    const float4* ep = (const float4*)(eattr + (size_t)eid * EDF);
    float4 v0 = ep[0], v1 = ep[1], v2 = ep[2], v3 = ep[3];
    union { f16x2 h[4]; float4 f; } a, b;
    a.h[0] = f16x2{(_Float16)v0.x, (_Float16)v0.y};
    a.h[1] = f16x2{(_Float16)v0.z, (_Float16)v0.w};
    a.h[2] = f16x2{(_Float16)v1.x, (_Float16)v1.y};
    a.h[3] = f16x2{(_Float16)v1.z, (_Float16)v1.w};
    b.h[0] = f16x2{(_Float16)v2.x, (_Float16)v2.y};
    b.h[1] = f16x2{(_Float16)v2.z, (_Float16)v2.w};
    b.h[2] = f16x2{(_Float16)v3.x, (_Float16)v3.y};
    b.h[3] = f16x2{(_Float16)v3.z, (_Float16)v3.w};
    csrea[(size_t)j * 2] = a.f;
    csrea[(size_t)j * 2 + 1] = b.f;
}

// ---------------- layer-1 input projections ----------------

__global__ __launch_bounds__(256) void proj_kernel(const float* __restrict__ x,
                                                   const float* __restrict__ ws,
                                                   const float* __restrict__ wd,
                                                   float* __restrict__ xs,
                                                   float* __restrict__ xd) {
    __shared__ float Ws[INF * HH], Wd[INF * HH];
    int tid = threadIdx.x;
    for (int i = tid; i < INF * HH; i += 256) { Ws[i] = ws[i]; Wd[i] = wd[i]; }
    __syncthreads();
    int gid = blockIdx.x * 256 + tid;
    if (gid >= NN * HH) return;
    int n = gid / HH, c = gid % HH;
    const float* xr = x + (size_t)n * INF;
    float as = 0.f, ad = 0.f;
    #pragma unroll
    for (int k = 0; k < INF; ++k) {
        float xv = xr[k];
        as = fmaf(xv, Ws[k * HH + c], as);
        ad = fmaf(xv, Wd[k * HH + c], ad);
    }
    xs[gid] = as;
    xd[gid] = ad;
}

// ------- GENConv softmax aggregation: constant-shift exp, f16 dot2, seq edge reads -------
// softmax with exp(msg-20): identical weights, overflow-safe (msg << 80), no running max.

__global__ __launch_bounds__(192) void agg_kernel(const float* __restrict__ xsrc,
                                                  const float* __restrict__ xdst,
                                                  const float4* __restrict__ csrea,
                                                  const float* __restrict__ w_edge,
                                                  const int* __restrict__ offs,
                                                  const int* __restrict__ csr_src,
                                                  float* __restrict__ hpre) {
    int node = blockIdx.x * 2 + (threadIdx.x / HH);
    int c = threadIdx.x % HH;
    f16x2 wc[8];
    #pragma unroll
    for (int k = 0; k < 8; ++k)
        wc[k] = f16x2{(_Float16)w_edge[(2 * k) * HH + c], (_Float16)w_edge[(2 * k + 1) * HH + c]};
    int s0 = offs[node], s1 = offs[node + 1];
    float num = 0.f, den = 0.f;
    if (s0 < s1) {
        union EA { float4 f; f16x2 h[4]; };
        EA n0, n1;
        int sn = csr_src[s0];
        n0.f = csrea[(size_t)s0 * 2];
        n1.f = csrea[(size_t)s0 * 2 + 1];
        for (int j = s0; j < s1; ++j) {
            int sn_c = sn;
            EA c0 = n0, c1 = n1;
            float xv = xsrc[sn_c * HH + c];
            if (j + 1 < s1) {  // prefetch next edge
                sn = csr_src[j + 1];
                n0.f = csrea[(size_t)(j + 1) * 2];
                n1.f = csrea[(size_t)(j + 1) * 2 + 1];
            }
            float acc = 0.f;
            #pragma unroll
            for (int k = 0; k < 4; ++k) acc = fdot2(c0.h[k], wc[k], acc);
            #pragma unroll
            for (int k = 0; k < 4; ++k) acc = fdot2(c1.h[k], wc[4 + k], acc);
            float msg = fmaxf(xv + acc, 0.f) + EPS_GEN;
            float p = __expf(msg - 20.f);
            den += p;
            num = fmaf(msg, p, num);
        }
    }
    float agg = (den > 0.f) ? (num / den) : 0.f;
    hpre[node * HH + c] = agg + xdst[node * HH + c];
}

// fp32 fallback (used only if workspace too small for csrea)
__global__ __launch_bounds__(192) void agg_f32_kernel(const float* __restrict__ xsrc,
                                                      const float* __restrict__ xdst,
                                                      const float* __restrict__ eattr,
                                                      const float* __restrict__ w_edge,
                                                      const int* __restrict__ offs,
                                                      const int* __restrict__ csr_src,
                                                      const int* __restrict__ csr_eid,
                                                      float* __restrict__ hpre) {
    int node = blockIdx.x * 2 + (threadIdx.x / HH);
    int c = threadIdx.x % HH;
    float wcf[EDF];
    #pragma unroll
    for (int k = 0; k < EDF; ++k) wcf[k] = w_edge[k * HH + c];
    int s0 = offs[node], s1 = offs[node + 1];
    float num = 0.f, den = 0.f;
    for (int j = s0; j < s1; ++j) {
        int sn = csr_src[j];
        int eid = csr_eid[j];
        const float* ea = eattr + (size_t)eid * EDF;
        float acc = 0.f;
        #pragma unroll
        for (int k = 0; k < EDF; ++k) acc = fmaf(ea[k], wcf[k], acc);
        float msg = fmaxf(xsrc[sn * HH + c] + acc, 0.f) + EPS_GEN;
        float p = __expf(msg - 20.f);
        den += p;
        num = fmaf(msg, p, num);
    }
    float agg = (den > 0.f) ? (num / den) : 0.f;
    hpre[node * HH + c] = agg + xdst[node * HH + c];
}

// ------- t = hpre @ mw1 [N,96]x[96,192]: 64-row tile, 2 cols/thread, + col stats -------

__global__ __launch_bounds__(192) void gemm1_kernel(const float* __restrict__ A,
                                                    const float* __restrict__ W,
                                                    float* __restrict__ T,
                                                    float* __restrict__ colsum,
                                                    float* __restrict__ colsumsq) {
    __shared__ float As[64 * HH];  // 24 KiB
    int n0 = blockIdx.x * 64, tid = threadIdx.x;
    int nrows = NN - n0; if (nrows > 64) nrows = 64;
    const float4* Ag = (const float4*)(A + (size_t)n0 * HH);
    int nvec = nrows * HH / 4;
    for (int i = tid; i < 64 * HH / 4; i += 192)
        ((float4*)As)[i] = (i < nvec) ? Ag[i] : float4{0.f, 0.f, 0.f, 0.f};
    __syncthreads();
    int c = tid % HH, nh = tid / HH;  // cols {c, c+96}, rows nh*32..+31
    float acc0[32], acc1[32];
    #pragma unroll
    for (int n = 0; n < 32; ++n) { acc0[n] = 0.f; acc1[n] = 0.f; }
    const float* Asr = As + nh * 32 * HH;
    for (int k = 0; k < HH; k += 4) {
        float b00 = W[(k + 0) * H2 + c], b01 = W[(k + 0) * H2 + c + HH];
        float b10 = W[(k + 1) * H2 + c], b11 = W[(k + 1) * H2 + c + HH];
        float b20 = W[(k + 2) * H2 + c], b21 = W[(k + 2) * H2 + c + HH];
        float b30 = W[(k + 3) * H2 + c], b31 = W[(k + 3) * H2 + c + HH];
        #pragma unroll
        for (int n = 0; n < 32; ++n) {
            float4 a4 = *(const float4*)(Asr + n * HH + k);
            acc0[n] = fmaf(a4.x, b00, fmaf(a4.y, b10, fmaf(a4.z, b20, fmaf(a4.w, b30, acc0[n]))));
            acc1[n] = fmaf(a4.x, b01, fmaf(a4.y, b11, fmaf(a4.z, b21, fmaf(a4.w, b31, acc1[n]))));
        }
    }
    float s0 = 0.f, ss0 = 0.f, s1 = 0.f, ss1 = 0.f;
    int rbase = n0 + nh * 32;
    for (int n = 0; n < 32; ++n) {
        if (rbase + n < NN) {
            float v0 = acc0[n], v1 = acc1[n];
            T[(size_t)(rbase + n) * H2 + c] = v0;
            T[(size_t)(rbase + n) * H2 + c + HH] = v1;
            s0 += v0; ss0 = fmaf(v0, v0, ss0);
            s1 += v1; ss1 = fmaf(v1, v1, ss1);
        }
    }
    __syncthreads();
    if (nh == 1) { As[c] = s0; As[c + 96] = ss0; As[c + 192] = s1; As[c + 288] = ss1; }
    __syncthreads();
    if (nh == 0) {
        atomicAdd(&colsum[c], s0 + As[c]);
        atomicAdd(&colsumsq[c], ss0 + As[c + 96]);
        atomicAdd(&colsum[c + HH], s1 + As[c + 192]);
        atomicAdd(&colsumsq[c + HH], ss1 + As[c + 288]);
    }
}

// ---------------- finalize BN affine: a=g*rsqrt(var+eps), b'=b-mu*a ----------------

__global__ __launch_bounds__(256) void finalize_bn(const float* __restrict__ colsum,
                                                   const float* __restrict__ colsumsq,
                                                   const float* __restrict__ g,
                                                   const float* __restrict__ b,
                                                   float* __restrict__ a_out,
                                                   float* __restrict__ b_out, int C) {
    int c = threadIdx.x;
    if (c >= C) return;
    const float invN = 1.f / (float)NN;
    float mu = colsum[c] * invN;
    float var = fmaxf(colsumsq[c] * invN - mu * mu, 0.f);
    float a = g[c] * rsqrtf(var + EPS_BN);
    a_out[c] = a;
    b_out[c] = b[c] - mu * a;
}

// ------- u = relu(bn(t)) @ mw2 [N,192]x[192,96]: 32-row tile, 2 cols/thread, + stats -------

__global__ __launch_bounds__(192) void gemm2_kernel(const float* __restrict__ T,
                                                    const float* __restrict__ W,
                                                    const float* __restrict__ a1,
                                                    const float* __restrict__ b1,
                                                    float* __restrict__ U,
                                                    float* __restrict__ colsum,
                                                    float* __restrict__ colsumsq) {
    __shared__ float As[32 * H2];  // 24 KiB
    int n0 = blockIdx.x * 32, tid = threadIdx.x;
    int nrows = NN - n0; if (nrows > 32) nrows = 32;
    const float4* Tg = (const float4*)(T + (size_t)n0 * H2);
    int nvec = nrows * H2 / 4;
    for (int i = tid; i < 32 * H2 / 4; i += 192) {
        float4 v = {0.f, 0.f, 0.f, 0.f};
        if (i < nvec) {
            float4 t = Tg[i];
            int k = (i % (H2 / 4)) * 4;
            float4 av = *(const float4*)(a1 + k), bv = *(const float4*)(b1 + k);
            v.x = fmaxf(fmaf(t.x, av.x, bv.x), 0.f);
            v.y = fmaxf(fmaf(t.y, av.y, bv.y), 0.f);
            v.z = fmaxf(fmaf(t.z, av.z, bv.z), 0.f);
            v.w = fmaxf(fmaf(t.w, av.w, bv.w), 0.f);
        }
        ((float4*)As)[i] = v;
    }
    __syncthreads();
    int c = tid % 48, ng = tid / 48;  // cols {c, c+48}, rows ng*8..+7
    float acc0[8], acc1[8];
    #pragma unroll
    for (int n = 0; n < 8; ++n) { acc0[n] = 0.f; acc1[n] = 0.f; }
    const float* Asr = As + ng * 8 * H2;
    for (int k = 0; k < H2; k += 4) {
        float b00 = W[(k + 0) * HH + c], b01 = W[(k + 0) * HH + c + 48];
        float b10 = W[(k + 1) * HH + c], b11 = W[(k + 1) * HH + c + 48];
        float b20 = W[(k + 2) * HH + c], b21 = W[(k + 2) * HH + c + 48];
        float b30 = W[(k + 3) * HH + c], b31 = W[(k + 3) * HH + c + 48];
        #pragma unroll
        for (int n = 0; n < 8; ++n) {
            float4 a4 = *(const float4*)(Asr + n * H2 + k);
            acc0[n] = fmaf(a4.x, b00, fmaf(a4.y, b10, fmaf(a4.z, b20, fmaf(a4.w, b30, acc0[n]))));
            acc1[n] = fmaf(a4.x, b01, fmaf(a4.y, b11, fmaf(a4.z, b21, fmaf(a4.w, b31, acc1[n]))));
        }
    }
    float s0 = 0.f, ss0 = 0.f, s1 = 0.f, ss1 = 0.f;
    int rbase = n0 + ng * 8;
    for (int n = 0; n < 8; ++n) {
        if (rbase + n < NN) {
            float v0 = acc0[n], v1 = acc1[n];
            U[(size_t)(rbase + n) * HH + c] = v0;
            U[(size_t)(rbase + n) * HH + c + 48] = v1;
            s0 += v0; ss0 = fmaf(v0, v0, ss0);
            s1 += v1; ss1 = fmaf(v1, v1, ss1);
        }
    }
    __syncthreads();
    if (ng > 0) {
        float* r = As + (ng - 1) * 192;
        r[c] = s0; r[c + 48] = ss0; r[c + 96] = s1; r[c + 144] = ss1;
    }
    __syncthreads();
    if (ng == 0) {
        for (int g = 0; g < 3; ++g) {
            s0 += As[g * 192 + c]; ss0 += As[g * 192 + c + 48];
            s1 += As[g * 192 + c + 96]; ss1 += As[g * 192 + c + 144];
        }
        atomicAdd(&colsum[c], s0);
        atomicAdd(&colsumsq[c], ss0);
        atomicAdd(&colsum[c + 48], s1);
        atomicAdd(&colsumsq[c + 48], ss1);
    }
}

// ---------------- h = relu(bn_out(u)), float4 ----------------

__global__ __launch_bounds__(256) void elem_kernel(const float* __restrict__ U,
                                                   const float* __restrict__ a2,
                                                   const float* __restrict__ b2,
                                                   float* __restrict__ Hout) {
    int i = blockIdx.x * 256 + threadIdx.x;
    if (i >= NN * HH / 4) return;
    float4 u = ((const float4*)U)[i];
    int k = (i % (HH / 4)) * 4;
    float4 av = *(const float4*)(a2 + k), bv = *(const float4*)(b2 + k);
    float4 h;
    h.x = fmaxf(fmaf(u.x, av.x, bv.x), 0.f);
    h.y = fmaxf(fmaf(u.y, av.y, bv.y), 0.f);
    h.z = fmaxf(fmaf(u.z, av.z, bv.z), 0.f);
    h.w = fmaxf(fmaf(u.w, av.w, bv.w), 0.f);
    ((float4*)Hout)[i] = h;
}

// ---------------- mean-pool: segmented register accumulation ----------------

__global__ __launch_bounds__(192) void pool_kernel(const float* __restrict__ Hfin,
                                                   const int* __restrict__ batch,
                                                   float* __restrict__ pool) {
    int n0 = blockIdx.x * NPB;
    int n1 = (n0 + NPB < NN) ? n0 + NPB : NN;
    int c = threadIdx.x % HH;
    int h = threadIdx.x / HH;  // 0 or 1
    float acc = 0.f;
    int gcur = -1;
    for (int n = n0 + h; n < n1; n += 2) {
        int g = batch[n];
        if (g != gcur) {
            if (gcur >= 0) atomicAdd(&pool[gcur * HH + c], acc);
            acc = 0.f;
            gcur = g;
        }
        acc += Hfin[n * HH + c];
    }
    if (gcur >= 0) atomicAdd(&pool[gcur * HH + c], acc);
}

__global__ __launch_bounds__(64) void cnt_kernel(const int* __restrict__ batch,
                                                 float* __restrict__ pcnt) {
    int g = threadIdx.x;
    if (g >= GG) return;
    int lo = 0, hi = NN;
    while (lo < hi) { int mid = (lo + hi) >> 1; if (batch[mid] < g) lo = mid + 1; else hi = mid; }
    int s = lo;
    lo = 0; hi = NN;
    while (lo < hi) { int mid = (lo + hi) >> 1; if (batch[mid] < g + 1) lo = mid + 1; else hi = mid; }
    pcnt[g] = (float)(lo - s);
}

__global__ __launch_bounds__(128) void out_kernel(const float* __restrict__ pool,
                                                  const float* __restrict__ pcnt,
                                                  const float* __restrict__ lw,
                                                  const float* __restrict__ lb,
                                                  float* __restrict__ out) {
    int g = blockIdx.x, o = threadIdx.x;
    float inv = 1.f / fmaxf(pcnt[g], 1.f);
    float acc = lb[o];
    for (int c = 0; c < HH; ++c) acc = fmaf(pool[g * HH + c] * inv, lw[c * OUTF + o], acc);
    out[(size_t)g * OUTF + o] = acc;
}

// ---------------- host ----------------

extern "C" void kernel_launch(void* const* d_in, const int* in_sizes, int n_in,
                              void* d_out, int out_size, void* d_ws, size_t ws_size,
                              hipStream_t stream) {
    const float* x = (const float*)d_in[0];
    const float* eattr = (const float*)d_in[1];
    const int* eidx = (const int*)d_in[2];
    const int* batch = (const int*)d_in[3];
    const float* w_src1 = (const float*)d_in[4];
    const float* w_dst1 = (const float*)d_in[5];
    const float* w_e[3] = {(const float*)d_in[6], (const float*)d_in[13], (const float*)d_in[20]};
    const float* mw1[3] = {(const float*)d_in[7], (const float*)d_in[14], (const float*)d_in[21]};
    const float* mg[3] = {(const float*)d_in[8], (const float*)d_in[15], (const float*)d_in[22]};
    const float* mb[3] = {(const float*)d_in[9], (const float*)d_in[16], (const float*)d_in[23]};
    const float* mw2[3] = {(const float*)d_in[10], (const float*)d_in[17], (const float*)d_in[24]};
    const float* bng[3] = {(const float*)d_in[11], (const float*)d_in[18], (const float*)d_in[25]};
    const float* bnb[3] = {(const float*)d_in[12], (const float*)d_in[19], (const float*)d_in[26]};
    const float* lin_w = (const float*)d_in[27];
    const float* lin_b = (const float*)d_in[28];
    float* out = (float*)d_out;

    const int* src = eidx;
    const int* dst = eidx + EE;

    // ---- workspace layout ----
    char* base = (char*)d_ws;
    size_t off = 0;
    int* deg = (int*)(base + off); off = align256(off + (size_t)NN * 4);
    int* cnt2 = (int*)(base + off); off = align256(off + (size_t)NN * 4);
    int* offs = (int*)(base + off); off = align256(off + (size_t)(NN + 1) * 4);
    int* bsum = (int*)(base + off); off = align256(off + (size_t)NB_SCAN * 4);
    int* csr_src = (int*)(base + off); off = align256(off + (size_t)EE * 4);
    int* csr_eid = (int*)(base + off); off = align256(off + (size_t)EE * 4);
    float* stats = (float*)(base + off); off = align256(off + 1152 * 4);
    float* colsum1 = stats;
    float* colsumsq1 = stats + 192;
    float* colsum2 = stats + 384;
    float* colsumsq2 = stats + 480;
    float* a1 = stats + 576;
    float* b1 = stats + 768;
    float* a2 = stats + 960;
    float* b2 = stats + 1056;
    float* pool = (float*)(base + off); off = align256(off + (size_t)GG * HH * 4);
    float* pcnt = (float*)(base + off); off = align256(off + (size_t)GG * 4);
    float* A = (float*)(base + off); off = align256(off + (size_t)NN * HH * 4);   // xs -> h
    float* B = (float*)(base + off); off = align256(off + (size_t)NN * HH * 4);   // hpre -> u
    float* C = (float*)(base + off); off = align256(off + (size_t)NN * H2 * 4);   // xd -> t
    float4* csrea = (float4*)(base + off); off = align256(off + (size_t)EE * 32); // f16 edge attrs, CSR order
    bool use16 = (ws_size >= off);
    (void)in_sizes; (void)n_in; (void)out_size;

    // ---- CSR build (parallel 2-level scan) ----
    hipMemsetAsync(deg, 0, (size_t)NN * 4, stream);
    hipMemsetAsync(cnt2, 0, (size_t)NN * 4, stream);
    hist_kernel<<<(EE + 255) / 256, 256, 0, stream>>>(dst, deg);
    scan1_kernel<<<NB_SCAN, 1024, 0, stream>>>(deg, offs, bsum);
    scan2_kernel<<<1, 64, 0, stream>>>(bsum);
    scan3_kernel<<<(NN + 255) / 256, 256, 0, stream>>>(offs, bsum);
    scatter_kernel<<<(EE + 255) / 256, 256, 0, stream>>>(src, dst, offs, cnt2, csr_src, csr_eid);
    if (use16)
        csrcvt_kernel<<<(EE + 255) / 256, 256, 0, stream>>>(csr_eid, eattr, csrea);

    // ---- layer-1 projections ----
    proj_kernel<<<(NN * HH + 255) / 256, 256, 0, stream>>>(x, w_src1, w_dst1, A, C);

    // ---- 3 GENConv layers ----
    for (int l = 0; l < 3; ++l) {
        const float* xsrc = A;
        const float* xdst = (l == 0) ? C : A;
        hipMemsetAsync(stats, 0, 576 * 4, stream);
        if (use16)
            agg_kernel<<<NN / 2, 192, 0, stream>>>(xsrc, xdst, csrea, w_e[l], offs, csr_src, B);
        else
            agg_f32_kernel<<<NN / 2, 192, 0, stream>>>(xsrc, xdst, eattr, w_e[l], offs,
                                                       csr_src, csr_eid, B);
        gemm1_kernel<<<(NN + 63) / 64, 192, 0, stream>>>(B, mw1[l], C, colsum1, colsumsq1);
        finalize_bn<<<1, 256, 0, stream>>>(colsum1, colsumsq1, mg[l], mb[l], a1, b1, H2);
        gemm2_kernel<<<(NN + 31) / 32, 192, 0, stream>>>(C, mw2[l], a1, b1, B, colsum2,
                                                         colsumsq2);
        finalize_bn<<<1, 256, 0, stream>>>(colsum2, colsumsq2, bng[l], bnb[l], a2, b2, HH);
        elem_kernel<<<(NN * HH / 4 + 255) / 256, 256, 0, stream>>>(B, a2, b2, A);
    }

    // ---- pooling + final linear ----
    hipMemsetAsync(pool, 0, (size_t)(GG * HH) * 4, stream);
    pool_kernel<<<(NN + NPB - 1) / NPB, 192, 0, stream>>>(A, batch, pool);
    cnt_kernel<<<1, 64, 0, stream>>>(batch, pcnt);
    out_kernel<<<GG, 128, 0, stream>>>(pool, pcnt, lin_w, lin_b, out);
}

// Round 4
// 799.303 us; speedup vs baseline: 2.4315x; 1.2224x over previous
//
#include <hip/hip_runtime.h>
#include <math.h>

#define NN 50000
#define EE 800000
#define GG 64
#define HH 96
#define H2 192
#define INF 32
#define EDF 16
#define OUTF 128
#define EPS_GEN 1e-7f
#define EPS_BN 1e-5f
#define NPB 100     // nodes per pool block
#define NB_SCAN 49  // ceil(NN/1024)
#define LOG2E 1.44269504088896f
#define SHIFT2 28.85390081777927f  // 20*log2e

typedef _Float16 f16;
typedef _Float16 f16x2 __attribute__((ext_vector_type(2)));

static inline size_t align256(size_t x) { return (x + 255) & ~(size_t)255; }

__device__ __forceinline__ float fdot2(f16x2 a, f16x2 b, float c) {
#if __has_builtin(__builtin_amdgcn_fdot2)
    return __builtin_amdgcn_fdot2(a, b, c, false);
#else
    return fmaf((float)a.x, (float)b.x, fmaf((float)a.y, (float)b.y, c));
#endif
}

__device__ __forceinline__ float exp2fast(float x) {
#if __has_builtin(__builtin_amdgcn_exp2f)
    return __builtin_amdgcn_exp2f(x);
#else
    return exp2f(x);
#endif
}

// ---------------- CSR build ----------------

__global__ __launch_bounds__(256) void hist_kernel(const int* __restrict__ dst,
                                                   int* __restrict__ deg) {
    int e = blockIdx.x * 256 + threadIdx.x;
    if (e >= EE) return;
    atomicAdd(&deg[dst[e]], 1);
}

__global__ __launch_bounds__(1024) void scan1_kernel(const int* __restrict__ deg,
                                                     int* __restrict__ offs,
                                                     int* __restrict__ bsum) {
    __shared__ int ws[16];
    int tid = threadIdx.x, lane = tid & 63, w = tid >> 6;
    int i = blockIdx.x * 1024 + tid;
    int v = (i < NN) ? deg[i] : 0;
    int x = v;
    #pragma unroll
    for (int off = 1; off < 64; off <<= 1) {
        int y = __shfl_up(x, off, 64);
        if (lane >= off) x += y;
    }
    if (lane == 63) ws[w] = x;
    __syncthreads();
    int wpre = 0;
    for (int j = 0; j < w; ++j) wpre += ws[j];
    if (i < NN) offs[i] = wpre + x - v;
    if (tid == 1023) bsum[blockIdx.x] = wpre + x;
}

__global__ __launch_bounds__(64) void scan2_kernel(int* __restrict__ bsum) {
    int lane = threadIdx.x;
    int v = (lane < NB_SCAN) ? bsum[lane] : 0;
    int x = v;
    #pragma unroll
    for (int off = 1; off < 64; off <<= 1) {
        int y = __shfl_up(x, off, 64);
        if (lane >= off) x += y;
    }
    if (lane < NB_SCAN) bsum[lane] = x - v;
}

__global__ __launch_bounds__(256) void scan3_kernel(int* __restrict__ offs,
                                                    const int* __restrict__ bsum) {
    int i = blockIdx.x * 256 + threadIdx.x;
    if (i < NN) offs[i] += bsum[i >> 10];
    if (i == 0) offs[NN] = EE;
}

__global__ __launch_bounds__(256) void scatter_kernel(const int* __restrict__ src,
                                                      const int* __restrict__ dst,
                                                      const int* __restrict__ offs,
                                                      int* __restrict__ cnt2,
                                                      int* __restrict__ csr_src,
                                                      int* __restrict__ csr_eid) {
    int e = blockIdx.x * 256 + threadIdx.x;
    if (e >= EE) return;
    int d = dst[e];
    int slot = offs[d] + atomicAdd(&cnt2[d], 1);
    csr_src[slot] = src[e];
    csr_eid[slot] = e;
}

// gather edge attrs into CSR order, f16 (32 B/slot → sequential reads in agg)
__global__ __launch_bounds__(256) void csrcvt_kernel(const int* __restrict__ csr_eid,
                                                     const float* __restrict__ eattr,
                                                     float4* __restrict__ csrea) {
    int j = blockIdx.x * 256 + threadIdx.x;
    if (j >= EE) return;
    int eid = csr_eid[j];
    const float4* ep = (const float4*)(eattr + (size_t)eid * EDF);
    float4 v0 = ep[0], v1 = ep[1], v2 = ep[2], v3 = ep[3];
    union { f16x2 h[4]; float4 f; } a, b;
    a.h[0] = f16x2{(f16)v0.x, (f16)v0.y};
    a.h[1] = f16x2{(f16)v0.z, (f16)v0.w};
    a.h[2] = f16x2{(f16)v1.x, (f16)v1.y};
    a.h[3] = f16x2{(f16)v1.z, (f16)v1.w};
    b.h[0] = f16x2{(f16)v2.x, (f16)v2.y};
    b.h[1] = f16x2{(f16)v2.z, (f16)v2.w};
    b.h[2] = f16x2{(f16)v3.x, (f16)v3.y};
    b.h[3] = f16x2{(f16)v3.z, (f16)v3.w};
    csrea[(size_t)j * 2] = a.f;
    csrea[(size_t)j * 2 + 1] = b.f;
}

// transpose+pack edge weights: wt[l][c][k] = (f16) w_l[k*96 + c]
__global__ __launch_bounds__(256) void wprep_kernel(const float* __restrict__ w0,
                                                    const float* __restrict__ w1,
                                                    const float* __restrict__ w2,
                                                    f16* __restrict__ wt) {
    int idx = blockIdx.x * 256 + threadIdx.x;
    if (idx >= 3 * HH * EDF) return;
    const float* w = (idx < 1536) ? w0 : ((idx < 3072) ? w1 : w2);
    int r = idx % 1536, c = r / EDF, k = r % EDF;
    wt[idx] = (f16)w[k * HH + c];
}

// ---------------- layer-1 input projections (f16 out) ----------------

__global__ __launch_bounds__(256) void proj_kernel(const float* __restrict__ x,
                                                   const float* __restrict__ ws,
                                                   const float* __restrict__ wd,
                                                   f16* __restrict__ xs,
                                                   f16* __restrict__ xd) {
    __shared__ float Ws[INF * HH], Wd[INF * HH];
    int tid = threadIdx.x;
    for (int i = tid; i < INF * HH; i += 256) { Ws[i] = ws[i]; Wd[i] = wd[i]; }
    __syncthreads();
    int gid = blockIdx.x * 256 + tid;
    if (gid >= NN * HH) return;
    int n = gid / HH, c = gid % HH;
    const float* xr = x + (size_t)n * INF;
    float as = 0.f, ad = 0.f;
    #pragma unroll
    for (int k = 0; k < INF; ++k) {
        float xv = xr[k];
        as = fmaf(xv, Ws[k * HH + c], as);
        ad = fmaf(xv, Wd[k * HH + c], ad);
    }
    xs[gid] = (f16)as;
    xd[gid] = (f16)ad;
}

// ------- GENConv softmax aggregation: 4 channels/thread, f16 states -------
// softmax weights via exp2(msg*log2e - 28.854) == exp(msg-20): shift cancels.

__global__ __launch_bounds__(192) void agg_kernel(const f16* __restrict__ xsrc,
                                                  const f16* __restrict__ xdst,
                                                  const float4* __restrict__ csrea,
                                                  const f16* __restrict__ wt,
                                                  const int* __restrict__ offs,
                                                  const int* __restrict__ csr_src,
                                                  f16* __restrict__ hpre) {
    int tid = threadIdx.x;
    int node = blockIdx.x * 8 + tid / 24;
    int cg = tid % 24, c0 = cg * 4;
    if (node >= NN) return;
    union W8 { float4 f[2]; f16x2 h[8]; };
    W8 w[4];
    #pragma unroll
    for (int cc = 0; cc < 4; ++cc) {
        const float4* wp = (const float4*)(wt + (c0 + cc) * EDF);
        w[cc].f[0] = wp[0];
        w[cc].f[1] = wp[1];
    }
    int s0 = offs[node], s1 = offs[node + 1];
    float num[4] = {0.f, 0.f, 0.f, 0.f}, den[4] = {0.f, 0.f, 0.f, 0.f};
    if (s0 < s1) {
        union EA { float4 f; f16x2 h[4]; };
        EA n0, n1;
        int sn = csr_src[s0];
        n0.f = csrea[(size_t)s0 * 2];
        n1.f = csrea[(size_t)s0 * 2 + 1];
        for (int j = s0; j < s1; ++j) {
            EA e0 = n0, e1 = n1;
            int sc = sn;
            union { float2 f; f16x2 h[2]; } xu;
            xu.f = *(const float2*)(xsrc + (size_t)sc * HH + c0);
            if (j + 1 < s1) {  // prefetch next edge
                sn = csr_src[j + 1];
                n0.f = csrea[(size_t)(j + 1) * 2];
                n1.f = csrea[(size_t)(j + 1) * 2 + 1];
            }
            float xv[4] = {(float)xu.h[0].x, (float)xu.h[0].y,
                           (float)xu.h[1].x, (float)xu.h[1].y};
            #pragma unroll
            for (int cc = 0; cc < 4; ++cc) {
                float acc = 0.f;
                #pragma unroll
                for (int k = 0; k < 4; ++k) acc = fdot2(e0.h[k], w[cc].h[k], acc);
                #pragma unroll
                for (int k = 0; k < 4; ++k) acc = fdot2(e1.h[k], w[cc].h[4 + k], acc);
                float msg = fmaxf(xv[cc] + acc, 0.f) + EPS_GEN;
                float p = exp2fast(fmaf(msg, LOG2E, -SHIFT2));
                den[cc] += p;
                num[cc] = fmaf(msg, p, num[cc]);
            }
        }
    }
    union { float2 f; f16x2 h[2]; } xd, o;
    xd.f = *(const float2*)(xdst + (size_t)node * HH + c0);
    float xdv[4] = {(float)xd.h[0].x, (float)xd.h[0].y, (float)xd.h[1].x, (float)xd.h[1].y};
    float r0 = (den[0] > 0.f) ? num[0] / den[0] : 0.f;
    float r1 = (den[1] > 0.f) ? num[1] / den[1] : 0.f;
    float r2 = (den[2] > 0.f) ? num[2] / den[2] : 0.f;
    float r3 = (den[3] > 0.f) ? num[3] / den[3] : 0.f;
    o.h[0] = f16x2{(f16)(r0 + xdv[0]), (f16)(r1 + xdv[1])};
    o.h[1] = f16x2{(f16)(r2 + xdv[2]), (f16)(r3 + xdv[3])};
    *(float2*)(hpre + (size_t)node * HH + c0) = o.f;
}

// ------- gemm1: T = hpre @ mw1 [N,96]x[96,192] f32-compute, 8-col blocking -------
#define LDA1 100  // padded LDS stride (100%32=4 breaks bank aliasing)

__global__ __launch_bounds__(192) void gemm1_kernel(const f16* __restrict__ A,
                                                    const float* __restrict__ W,
                                                    f16* __restrict__ T,
                                                    float* __restrict__ colsum,
                                                    float* __restrict__ colsumsq) {
    __shared__ float As[64 * LDA1];
    int n0 = blockIdx.x * 64, tid = threadIdx.x;
    int nrows = NN - n0; if (nrows > 64) nrows = 64;
    const float4* src = (const float4*)(A + (size_t)n0 * HH);
    int nvec = nrows * HH / 8;
    for (int v = tid; v < 64 * HH / 8; v += 192) {
        union { float4 f; f16x2 h[4]; } u;
        u.f = (v < nvec) ? src[v] : float4{0.f, 0.f, 0.f, 0.f};
        int row = v / 12, col = (v % 12) * 8;
        float* d = &As[row * LDA1 + col];
        *(float4*)d = float4{(float)u.h[0].x, (float)u.h[0].y, (float)u.h[1].x, (float)u.h[1].y};
        *(float4*)(d + 4) = float4{(float)u.h[2].x, (float)u.h[2].y, (float)u.h[3].x, (float)u.h[3].y};
    }
    __syncthreads();
    int cg = tid % 24, rg = tid / 24;  // cols cg+24*cc (cc<8), rows rg*8..+7
    float acc[8][8];
    #pragma unroll
    for (int n = 0; n < 8; ++n)
        #pragma unroll
        for (int cc = 0; cc < 8; ++cc) acc[n][cc] = 0.f;
    const float* Asr = As + rg * 8 * LDA1;
    for (int k = 0; k < HH; k += 4) {
        float b[4][8];
        #pragma unroll
        for (int kk = 0; kk < 4; ++kk) {
            const float* wr = W + (k + kk) * H2 + cg;
            #pragma unroll
            for (int cc = 0; cc < 8; ++cc) b[kk][cc] = wr[cc * 24];
        }
        #pragma unroll
        for (int n = 0; n < 8; ++n) {
            float4 a4 = *(const float4*)(Asr + n * LDA1 + k);
            #pragma unroll
            for (int cc = 0; cc < 8; ++cc)
                acc[n][cc] = fmaf(a4.x, b[0][cc], fmaf(a4.y, b[1][cc],
                             fmaf(a4.z, b[2][cc], fmaf(a4.w, b[3][cc], acc[n][cc]))));
        }
    }
    float s[8], ss[8];
    #pragma unroll
    for (int cc = 0; cc < 8; ++cc) { s[cc] = 0.f; ss[cc] = 0.f; }
    int rbase = n0 + rg * 8;
    for (int n = 0; n < 8; ++n) {
        if (rbase + n < NN) {
            #pragma unroll
            for (int cc = 0; cc < 8; ++cc) {
                float v = acc[n][cc];
                T[(size_t)(rbase + n) * H2 + cg + cc * 24] = (f16)v;
                s[cc] += v;
                ss[cc] = fmaf(v, v, ss[cc]);
            }
        }
    }
    __syncthreads();  // reuse As for stats reduce: 8 rowgroups x 192 cols x 2
    #pragma unroll
    for (int cc = 0; cc < 8; ++cc) {
        float* p = &As[(rg * H2 + cg + cc * 24) * 2];
        p[0] = s[cc]; p[1] = ss[cc];
    }
    __syncthreads();
    if (tid < H2) {
        float S = 0.f, SS = 0.f;
        for (int r = 0; r < 8; ++r) { S += As[(r * H2 + tid) * 2]; SS += As[(r * H2 + tid) * 2 + 1]; }
        atomicAdd(&colsum[tid], S);
        atomicAdd(&colsumsq[tid], SS);
    }
}

// ---------------- finalize BN affine ----------------

__global__ __launch_bounds__(256) void finalize_bn(const float* __restrict__ colsum,
                                                   const float* __restrict__ colsumsq,
                                                   const float* __restrict__ g,
                                                   const float* __restrict__ b,
                                                   float* __restrict__ a_out,
                                                   float* __restrict__ b_out, int C) {
    int c = threadIdx.x;
    if (c >= C) return;
    const float invN = 1.f / (float)NN;
    float mu = colsum[c] * invN;
    float var = fmaxf(colsumsq[c] * invN - mu * mu, 0.f);
    float a = g[c] * rsqrtf(var + EPS_BN);
    a_out[c] = a;
    b_out[c] = b[c] - mu * a;
}

// ------- gemm2: U = relu(bn(T)) @ mw2 [N,192]x[192,96], 8-col blocking -------
#define LDA2 196  // 196%32=4

__global__ __launch_bounds__(192) void gemm2_kernel(const f16* __restrict__ T,
                                                    const float* __restrict__ W,
                                                    const float* __restrict__ a1,
                                                    const float* __restrict__ b1,
                                                    f16* __restrict__ U,
                                                    float* __restrict__ colsum,
                                                    float* __restrict__ colsumsq) {
    __shared__ float As[64 * LDA2];  // ~50 KB
    int n0 = blockIdx.x * 64, tid = threadIdx.x;
    int nrows = NN - n0; if (nrows > 64) nrows = 64;
    const float4* src = (const float4*)(T + (size_t)n0 * H2);
    int nvec = nrows * H2 / 8;
    for (int v = tid; v < 64 * H2 / 8; v += 192) {
        union { float4 f; f16x2 h[4]; } u;
        u.f = (v < nvec) ? src[v] : float4{0.f, 0.f, 0.f, 0.f};
        int row = v / 24, k = (v % 24) * 8;
        float4 av0 = *(const float4*)(a1 + k), av1 = *(const float4*)(a1 + k + 4);
        float4 bv0 = *(const float4*)(b1 + k), bv1 = *(const float4*)(b1 + k + 4);
        float* d = &As[row * LDA2 + k];
        *(float4*)d = float4{fmaxf(fmaf((float)u.h[0].x, av0.x, bv0.x), 0.f),
                             fmaxf(fmaf((float)u.h[0].y, av0.y, bv0.y), 0.f),
                             fmaxf(fmaf((float)u.h[1].x, av0.z, bv0.z), 0.f),
                             fmaxf(fmaf((float)u.h[1].y, av0.w, bv0.w), 0.f)};
        *(float4*)(d + 4) = float4{fmaxf(fmaf((float)u.h[2].x, av1.x, bv1.x), 0.f),
                                   fmaxf(fmaf((float)u.h[2].y, av1.y, bv1.y), 0.f),
                                   fmaxf(fmaf((float)u.h[3].x, av1.z, bv1.z), 0.f),
                                   fmaxf(fmaf((float)u.h[3].y, av1.w, bv1.w), 0.f)};
    }
    __syncthreads();
    int cg = tid % 12, rg = tid / 12;  // cols cg+12*cc (cc<8), rows rg*4..+3
    float acc[4][8];
    #pragma unroll
    for (int n = 0; n < 4; ++n)
        #pragma unroll
        for (int cc = 0; cc < 8; ++cc) acc[n][cc] = 0.f;
    const float* Asr = As + rg * 4 * LDA2;
    for (int k = 0; k < H2; k += 4) {
        float b[4][8];
        #pragma unroll
        for (int kk = 0; kk < 4; ++kk) {
            const float* wr = W + (k + kk) * HH + cg;
            #pragma unroll
            for (int cc = 0; cc < 8; ++cc) b[kk][cc] = wr[cc * 12];
        }
        #pragma unroll
        for (int n = 0; n < 4; ++n) {
            float4 a4 = *(const float4*)(Asr + n * LDA2 + k);
            #pragma unroll
            for (int cc = 0; cc < 8; ++cc)
                acc[n][cc] = fmaf(a4.x, b[0][cc], fmaf(a4.y, b[1][cc],
                             fmaf(a4.z, b[2][cc], fmaf(a4.w, b[3][cc], acc[n][cc]))));
        }
    }
    float s[8], ss[8];
    #pragma unroll
    for (int cc = 0; cc < 8; ++cc) { s[cc] = 0.f; ss[cc] = 0.f; }
    int rbase = n0 + rg * 4;
    for (int n = 0; n < 4; ++n) {
        if (rbase + n < NN) {
            #pragma unroll
            for (int cc = 0; cc < 8; ++cc) {
                float v = acc[n][cc];
                U[(size_t)(rbase + n) * HH + cg + cc * 12] = (f16)v;
                s[cc] += v;
                ss[cc] = fmaf(v, v, ss[cc]);
            }
        }
    }
    __syncthreads();  // stats reduce: 16 rowgroups x 96 cols x 2 = 3072 floats
    #pragma unroll
    for (int cc = 0; cc < 8; ++cc) {
        float* p = &As[(rg * HH + cg + cc * 12) * 2];
        p[0] = s[cc]; p[1] = ss[cc];
    }
    __syncthreads();
    if (tid < HH) {
        float S = 0.f, SS = 0.f;
        for (int r = 0; r < 16; ++r) { S += As[(r * HH + tid) * 2]; SS += As[(r * HH + tid) * 2 + 1]; }
        atomicAdd(&colsum[tid], S);
        atomicAdd(&colsumsq[tid], SS);
    }
}

// ---------------- h = relu(bn_out(u)), 8 f16/thread ----------------

__global__ __launch_bounds__(256) void elem_kernel(const f16* __restrict__ U,
                                                   const float* __restrict__ a2,
                                                   const float* __restrict__ b2,
                                                   f16* __restrict__ Hout) {
    int i = blockIdx.x * 256 + threadIdx.x;
    if (i >= NN * HH / 8) return;
    union { float4 f; f16x2 h[4]; } u, o;
    u.f = ((const float4*)U)[i];
    int k = (i % 12) * 8;
    float4 a0 = *(const float4*)(a2 + k), a1v = *(const float4*)(a2 + k + 4);
    float4 b0 = *(const float4*)(b2 + k), b1v = *(const float4*)(b2 + k + 4);
    o.h[0] = f16x2{(f16)fmaxf(fmaf((float)u.h[0].x, a0.x, b0.x), 0.f),
                   (f16)fmaxf(fmaf((float)u.h[0].y, a0.y, b0.y), 0.f)};
    o.h[1] = f16x2{(f16)fmaxf(fmaf((float)u.h[1].x, a0.z, b0.z), 0.f),
                   (f16)fmaxf(fmaf((float)u.h[1].y, a0.w, b0.w), 0.f)};
    o.h[2] = f16x2{(f16)fmaxf(fmaf((float)u.h[2].x, a1v.x, b1v.x), 0.f),
                   (f16)fmaxf(fmaf((float)u.h[2].y, a1v.y, b1v.y), 0.f)};
    o.h[3] = f16x2{(f16)fmaxf(fmaf((float)u.h[3].x, a1v.z, b1v.z), 0.f),
                   (f16)fmaxf(fmaf((float)u.h[3].y, a1v.w, b1v.w), 0.f)};
    ((float4*)Hout)[i] = o.f;
}

// ---------------- mean-pool: segmented register accumulation ----------------

__global__ __launch_bounds__(192) void pool_kernel(const f16* __restrict__ Hfin,
                                                   const int* __restrict__ batch,
                                                   float* __restrict__ pool) {
    int n0 = blockIdx.x * NPB;
    int n1 = (n0 + NPB < NN) ? n0 + NPB : NN;
    int c = threadIdx.x % HH;
    int h = threadIdx.x / HH;
    float acc = 0.f;
    int gcur = -1;
    for (int n = n0 + h; n < n1; n += 2) {
        int g = batch[n];
        if (g != gcur) {
            if (gcur >= 0) atomicAdd(&pool[gcur * HH + c], acc);
            acc = 0.f;
            gcur = g;
        }
        acc += (float)Hfin[(size_t)n * HH + c];
    }
    if (gcur >= 0) atomicAdd(&pool[gcur * HH + c], acc);
}

__global__ __launch_bounds__(64) void cnt_kernel(const int* __restrict__ batch,
                                                 float* __restrict__ pcnt) {
    int g = threadIdx.x;
    if (g >= GG) return;
    int lo = 0, hi = NN;
    while (lo < hi) { int mid = (lo + hi) >> 1; if (batch[mid] < g) lo = mid + 1; else hi = mid; }
    int s = lo;
    lo = 0; hi = NN;
    while (lo < hi) { int mid = (lo + hi) >> 1; if (batch[mid] < g + 1) lo = mid + 1; else hi = mid; }
    pcnt[g] = (float)(lo - s);
}

__global__ __launch_bounds__(128) void out_kernel(const float* __restrict__ pool,
                                                  const float* __restrict__ pcnt,
                                                  const float* __restrict__ lw,
                                                  const float* __restrict__ lb,
                                                  float* __restrict__ out) {
    int g = blockIdx.x, o = threadIdx.x;
    float inv = 1.f / fmaxf(pcnt[g], 1.f);
    float acc = lb[o];
    for (int c = 0; c < HH; ++c) acc = fmaf(pool[g * HH + c] * inv, lw[c * OUTF + o], acc);
    out[(size_t)g * OUTF + o] = acc;
}

// ---------------- host ----------------

extern "C" void kernel_launch(void* const* d_in, const int* in_sizes, int n_in,
                              void* d_out, int out_size, void* d_ws, size_t ws_size,
                              hipStream_t stream) {
    const float* x = (const float*)d_in[0];
    const float* eattr = (const float*)d_in[1];
    const int* eidx = (const int*)d_in[2];
    const int* batch = (const int*)d_in[3];
    const float* w_src1 = (const float*)d_in[4];
    const float* w_dst1 = (const float*)d_in[5];
    const float* w_e[3] = {(const float*)d_in[6], (const float*)d_in[13], (const float*)d_in[20]};
    const float* mw1[3] = {(const float*)d_in[7], (const float*)d_in[14], (const float*)d_in[21]};
    const float* mg[3] = {(const float*)d_in[8], (const float*)d_in[15], (const float*)d_in[22]};
    const float* mb[3] = {(const float*)d_in[9], (const float*)d_in[16], (const float*)d_in[23]};
    const float* mw2[3] = {(const float*)d_in[10], (const float*)d_in[17], (const float*)d_in[24]};
    const float* bng[3] = {(const float*)d_in[11], (const float*)d_in[18], (const float*)d_in[25]};
    const float* bnb[3] = {(const float*)d_in[12], (const float*)d_in[19], (const float*)d_in[26]};
    const float* lin_w = (const float*)d_in[27];
    const float* lin_b = (const float*)d_in[28];
    float* out = (float*)d_out;

    const int* src = eidx;
    const int* dst = eidx + EE;

    // ---- workspace layout ----
    char* base = (char*)d_ws;
    size_t off = 0;
    int* deg = (int*)(base + off); off = align256(off + (size_t)NN * 4);
    int* cnt2 = (int*)(base + off); off = align256(off + (size_t)NN * 4);
    int* offs = (int*)(base + off); off = align256(off + (size_t)(NN + 1) * 4);
    int* bsum = (int*)(base + off); off = align256(off + (size_t)NB_SCAN * 4);
    int* csr_src = (int*)(base + off); off = align256(off + (size_t)EE * 4);
    int* csr_eid = (int*)(base + off); off = align256(off + (size_t)EE * 4);
    float* stats = (float*)(base + off); off = align256(off + 1152 * 4);
    float* colsum1 = stats;
    float* colsumsq1 = stats + 192;
    float* colsum2 = stats + 384;
    float* colsumsq2 = stats + 480;
    float* a1 = stats + 576;
    float* b1 = stats + 768;
    float* a2 = stats + 960;
    float* b2 = stats + 1056;
    float* pool = (float*)(base + off); off = align256(off + (size_t)GG * HH * 4);
    float* pcnt = (float*)(base + off); off = align256(off + (size_t)GG * 4);
    f16* wt = (f16*)(base + off); off = align256(off + (size_t)3 * HH * EDF * 2);
    f16* XS = (f16*)(base + off); off = align256(off + (size_t)NN * HH * 2);   // xs -> h
    f16* XD = (f16*)(base + off); off = align256(off + (size_t)NN * HH * 2);   // xd (layer1)
    f16* HP = (f16*)(base + off); off = align256(off + (size_t)NN * HH * 2);   // hpre -> U
    f16* T = (f16*)(base + off); off = align256(off + (size_t)NN * H2 * 2);
    float4* csrea = (float4*)(base + off); off = align256(off + (size_t)EE * 32);
    (void)in_sizes; (void)n_in; (void)out_size; (void)ws_size;

    // ---- CSR build ----
    hipMemsetAsync(deg, 0, (size_t)NN * 4, stream);
    hipMemsetAsync(cnt2, 0, (size_t)NN * 4, stream);
    hist_kernel<<<(EE + 255) / 256, 256, 0, stream>>>(dst, deg);
    scan1_kernel<<<NB_SCAN, 1024, 0, stream>>>(deg, offs, bsum);
    scan2_kernel<<<1, 64, 0, stream>>>(bsum);
    scan3_kernel<<<(NN + 255) / 256, 256, 0, stream>>>(offs, bsum);
    scatter_kernel<<<(EE + 255) / 256, 256, 0, stream>>>(src, dst, offs, cnt2, csr_src, csr_eid);
    csrcvt_kernel<<<(EE + 255) / 256, 256, 0, stream>>>(csr_eid, eattr, csrea);
    wprep_kernel<<<(3 * HH * EDF + 255) / 256, 256, 0, stream>>>(w_e[0], w_e[1], w_e[2], wt);

    // ---- layer-1 projections ----
    proj_kernel<<<(NN * HH + 255) / 256, 256, 0, stream>>>(x, w_src1, w_dst1, XS, XD);

    // ---- 3 GENConv layers ----
    for (int l = 0; l < 3; ++l) {
        const f16* xdst = (l == 0) ? XD : XS;
        hipMemsetAsync(stats, 0, 576 * 4, stream);
        agg_kernel<<<(NN + 7) / 8, 192, 0, stream>>>(XS, xdst, csrea, wt + l * 1536, offs,
                                                     csr_src, HP);
        gemm1_kernel<<<(NN + 63) / 64, 192, 0, stream>>>(HP, mw1[l], T, colsum1, colsumsq1);
        finalize_bn<<<1, 256, 0, stream>>>(colsum1, colsumsq1, mg[l], mb[l], a1, b1, H2);
        gemm2_kernel<<<(NN + 63) / 64, 192, 0, stream>>>(T, mw2[l], a1, b1, HP, colsum2,
                                                         colsumsq2);
        finalize_bn<<<1, 256, 0, stream>>>(colsum2, colsumsq2, bng[l], bnb[l], a2, b2, HH);
        elem_kernel<<<(NN * HH / 8 + 255) / 256, 256, 0, stream>>>(HP, a2, b2, XS);
    }

    // ---- pooling + final linear ----
    hipMemsetAsync(pool, 0, (size_t)(GG * HH) * 4, stream);
    pool_kernel<<<(NN + NPB - 1) / NPB, 192, 0, stream>>>(XS, batch, pool);
    cnt_kernel<<<1, 64, 0, stream>>>(batch, pcnt);
    out_kernel<<<GG, 128, 0, stream>>>(pool, pcnt, lin_w, lin_b, out);
}

// Round 5
// 640.626 us; speedup vs baseline: 3.0338x; 1.2477x over previous
//
#include <hip/hip_runtime.h>
#include <math.h>

#define NN 50000
#define EE 800000
#define GG 64
#define HH 96
#define H2 192
#define INF 32
#define EDF 16
#define OUTF 128
#define EPS_GEN 1e-7f
#define EPS_BN 1e-5f
#define NPB 100     // nodes per pool block
#define NB_SCAN 49  // ceil(NN/1024)
#define LOG2E 1.44269504088896f
#define SHIFT2 28.85390081777927f  // 20*log2e

typedef _Float16 f16;
typedef _Float16 f16x2 __attribute__((ext_vector_type(2)));
typedef _Float16 f16x8 __attribute__((ext_vector_type(8)));
typedef float f32x4 __attribute__((ext_vector_type(4)));

static inline size_t align256(size_t x) { return (x + 255) & ~(size_t)255; }

__device__ __forceinline__ float fdot2(f16x2 a, f16x2 b, float c) {
#if __has_builtin(__builtin_amdgcn_fdot2)
    return __builtin_amdgcn_fdot2(a, b, c, false);
#else
    return fmaf((float)a.x, (float)b.x, fmaf((float)a.y, (float)b.y, c));
#endif
}

__device__ __forceinline__ float exp2fast(float x) {
#if __has_builtin(__builtin_amdgcn_exp2f)
    return __builtin_amdgcn_exp2f(x);
#else
    return exp2f(x);
#endif
}

// ---------------- CSR build ----------------

__global__ __launch_bounds__(256) void hist_kernel(const int* __restrict__ dst,
                                                   int* __restrict__ deg) {
    int e = blockIdx.x * 256 + threadIdx.x;
    if (e >= EE) return;
    atomicAdd(&deg[dst[e]], 1);
}

__global__ __launch_bounds__(1024) void scan1_kernel(const int* __restrict__ deg,
                                                     int* __restrict__ offs,
                                                     int* __restrict__ bsum) {
    __shared__ int ws[16];
    int tid = threadIdx.x, lane = tid & 63, w = tid >> 6;
    int i = blockIdx.x * 1024 + tid;
    int v = (i < NN) ? deg[i] : 0;
    int x = v;
    #pragma unroll
    for (int off = 1; off < 64; off <<= 1) {
        int y = __shfl_up(x, off, 64);
        if (lane >= off) x += y;
    }
    if (lane == 63) ws[w] = x;
    __syncthreads();
    int wpre = 0;
    for (int j = 0; j < w; ++j) wpre += ws[j];
    if (i < NN) offs[i] = wpre + x - v;
    if (tid == 1023) bsum[blockIdx.x] = wpre + x;
}

__global__ __launch_bounds__(64) void scan2_kernel(int* __restrict__ bsum) {
    int lane = threadIdx.x;
    int v = (lane < NB_SCAN) ? bsum[lane] : 0;
    int x = v;
    #pragma unroll
    for (int off = 1; off < 64; off <<= 1) {
        int y = __shfl_up(x, off, 64);
        if (lane >= off) x += y;
    }
    if (lane < NB_SCAN) bsum[lane] = x - v;
}

__global__ __launch_bounds__(256) void scan3_kernel(int* __restrict__ offs,
                                                    const int* __restrict__ bsum) {
    int i = blockIdx.x * 256 + threadIdx.x;
    if (i < NN) offs[i] += bsum[i >> 10];
    if (i == 0) offs[NN] = EE;
}

// scatter with fused f16 conversion: sequential eattr read, scattered 32B csrea write
__global__ __launch_bounds__(256) void scatter_kernel(const int* __restrict__ src,
                                                      const int* __restrict__ dst,
                                                      const int* __restrict__ offs,
                                                      int* __restrict__ cnt2,
                                                      const float* __restrict__ eattr,
                                                      int* __restrict__ csr_src,
                                                      float4* __restrict__ csrea) {
    int e = blockIdx.x * 256 + threadIdx.x;
    if (e >= EE) return;
    int d = dst[e];
    int slot = offs[d] + atomicAdd(&cnt2[d], 1);
    csr_src[slot] = src[e];
    const float4* ep = (const float4*)(eattr + (size_t)e * EDF);
    float4 v0 = ep[0], v1 = ep[1], v2 = ep[2], v3 = ep[3];
    union { f16x2 h[4]; float4 f; } a, b;
    a.h[0] = f16x2{(f16)v0.x, (f16)v0.y};
    a.h[1] = f16x2{(f16)v0.z, (f16)v0.w};
    a.h[2] = f16x2{(f16)v1.x, (f16)v1.y};
    a.h[3] = f16x2{(f16)v1.z, (f16)v1.w};
    b.h[0] = f16x2{(f16)v2.x, (f16)v2.y};
    b.h[1] = f16x2{(f16)v2.z, (f16)v2.w};
    b.h[2] = f16x2{(f16)v3.x, (f16)v3.y};
    b.h[3] = f16x2{(f16)v3.z, (f16)v3.w};
    csrea[(size_t)slot * 2] = a.f;
    csrea[(size_t)slot * 2 + 1] = b.f;
}

// ---- weight prep: edge weights [c][k] f16; mw1 -> [j][k] f16 (192x96); mw2 -> [j][k] (96x192)
__global__ __launch_bounds__(256) void wprep_kernel(
    const float* __restrict__ we0, const float* __restrict__ we1, const float* __restrict__ we2,
    const float* __restrict__ m10, const float* __restrict__ m11, const float* __restrict__ m12,
    const float* __restrict__ m20, const float* __restrict__ m21, const float* __restrict__ m22,
    f16* __restrict__ wte, f16* __restrict__ wt1, f16* __restrict__ wt2) {
    int idx = blockIdx.x * 256 + threadIdx.x;
    if (idx < 4608) {
        const float* w = (idx < 1536) ? we0 : ((idx < 3072) ? we1 : we2);
        int r = idx % 1536, c = r / EDF, k = r % EDF;
        wte[idx] = (f16)w[k * HH + c];
    } else if (idx < 4608 + 3 * 18432) {
        int m = idx - 4608;
        const float* w = (m < 18432) ? m10 : ((m < 36864) ? m11 : m12);
        int r = m % 18432, j = r / HH, k = r % HH;  // [192][96]
        wt1[m] = (f16)w[k * H2 + j];
    } else if (idx < 4608 + 6 * 18432) {
        int m = idx - 4608 - 3 * 18432;
        const float* w = (m < 18432) ? m20 : ((m < 36864) ? m21 : m22);
        int r = m % 18432, j = r / H2, k = r % H2;  // [96][192]
        wt2[m] = (f16)w[k * HH + j];
    }
}

// ---------------- layer-1 input projections (f16 out) ----------------

__global__ __launch_bounds__(256) void proj_kernel(const float* __restrict__ x,
                                                   const float* __restrict__ ws,
                                                   const float* __restrict__ wd,
                                                   f16* __restrict__ xs,
                                                   f16* __restrict__ xd) {
    __shared__ float Ws[INF * HH], Wd[INF * HH];
    int tid = threadIdx.x;
    for (int i = tid; i < INF * HH; i += 256) { Ws[i] = ws[i]; Wd[i] = wd[i]; }
    __syncthreads();
    int gid = blockIdx.x * 256 + tid;
    if (gid >= NN * HH) return;
    int n = gid / HH, c = gid % HH;
    const float* xr = x + (size_t)n * INF;
    float as = 0.f, ad = 0.f;
    #pragma unroll
    for (int k = 0; k < INF; ++k) {
        float xv = xr[k];
        as = fmaf(xv, Ws[k * HH + c], as);
        ad = fmaf(xv, Wd[k * HH + c], ad);
    }
    xs[gid] = (f16)as;
    xd[gid] = (f16)ad;
}

// ------- GENConv softmax aggregation: 4 ch/thread, deep prefetch pipeline -------

__global__ __launch_bounds__(192) void agg_kernel(const f16* __restrict__ xsrc,
                                                  const f16* __restrict__ xdst,
                                                  const float4* __restrict__ csrea,
                                                  const f16* __restrict__ wt,
                                                  const int* __restrict__ offs,
                                                  const int* __restrict__ csr_src,
                                                  f16* __restrict__ hpre) {
    int tid = threadIdx.x;
    int node = blockIdx.x * 8 + tid / 24;
    int cg = tid % 24, c0 = cg * 4;
    if (node >= NN) return;
    union W8 { float4 f[2]; f16x2 h[8]; };
    W8 w[4];
    #pragma unroll
    for (int cc = 0; cc < 4; ++cc) {
        const float4* wp = (const float4*)(wt + (c0 + cc) * EDF);
        w[cc].f[0] = wp[0];
        w[cc].f[1] = wp[1];
    }
    int s0 = offs[node], s1 = offs[node + 1];
    float num[4] = {0.f, 0.f, 0.f, 0.f}, den[4] = {0.f, 0.f, 0.f, 0.f};
    if (s0 < s1) {
        int last = s1 - 1;
        union EA { float4 f; f16x2 h[4]; };
        union XU { float2 f; f16x2 h[2]; };
        EA ea0, ea1;
        XU xu;
        int sn_cur = csr_src[s0];
        ea0.f = csrea[(size_t)s0 * 2];
        ea1.f = csrea[(size_t)s0 * 2 + 1];
        xu.f = *(const float2*)(xsrc + (size_t)sn_cur * HH + c0);
        int sn_nxt = csr_src[(s0 < last) ? s0 + 1 : last];
        for (int j = s0; j <= last; ++j) {
            // issue all loads for j+1 (clamped; values shifted in next iter)
            int jn = (j < last) ? j + 1 : last;
            int jnn = (j + 2 < last) ? j + 2 : last;
            EA na, nb;
            XU xn;
            na.f = csrea[(size_t)jn * 2];
            nb.f = csrea[(size_t)jn * 2 + 1];
            xn.f = *(const float2*)(xsrc + (size_t)sn_nxt * HH + c0);
            int sn_nn = csr_src[jnn];
            // compute on current
            float xv[4] = {(float)xu.h[0].x, (float)xu.h[0].y,
                           (float)xu.h[1].x, (float)xu.h[1].y};
            #pragma unroll
            for (int cc = 0; cc < 4; ++cc) {
                float acc = 0.f;
                #pragma unroll
                for (int k = 0; k < 4; ++k) acc = fdot2(ea0.h[k], w[cc].h[k], acc);
                #pragma unroll
                for (int k = 0; k < 4; ++k) acc = fdot2(ea1.h[k], w[cc].h[4 + k], acc);
                float msg = fmaxf(xv[cc] + acc, 0.f) + EPS_GEN;
                float p = exp2fast(fmaf(msg, LOG2E, -SHIFT2));
                den[cc] += p;
                num[cc] = fmaf(msg, p, num[cc]);
            }
            ea0 = na; ea1 = nb; xu = xn; sn_nxt = sn_nn;
        }
    }
    union { float2 f; f16x2 h[2]; } xd, o;
    xd.f = *(const float2*)(xdst + (size_t)node * HH + c0);
    float xdv[4] = {(float)xd.h[0].x, (float)xd.h[0].y, (float)xd.h[1].x, (float)xd.h[1].y};
    float r0 = (den[0] > 0.f) ? num[0] / den[0] : 0.f;
    float r1 = (den[1] > 0.f) ? num[1] / den[1] : 0.f;
    float r2 = (den[2] > 0.f) ? num[2] / den[2] : 0.f;
    float r3 = (den[3] > 0.f) ? num[3] / den[3] : 0.f;
    o.h[0] = f16x2{(f16)(r0 + xdv[0]), (f16)(r1 + xdv[1])};
    o.h[1] = f16x2{(f16)(r2 + xdv[2]), (f16)(r3 + xdv[3])};
    *(float2*)(hpre + (size_t)node * HH + c0) = o.f;
}

// ------- gemm1 (MFMA): T = HP @ mw1  [N,96]x[96,192], f16 in, f32 acc, + col stats -------
#define LDA1 104  // f16 units, 16B-aligned rows, breaks bank aliasing

__global__ __launch_bounds__(256) void gemm1_kernel(const f16* __restrict__ A,
                                                    const f16* __restrict__ Wt,
                                                    f16* __restrict__ T,
                                                    float* __restrict__ colsum,
                                                    float* __restrict__ colsumsq) {
    __shared__ f16 Al[64 * LDA1];
    __shared__ f16 Wl[192 * LDA1];
    __shared__ float red[H2 * 2];
    int tid = threadIdx.x, n0 = blockIdx.x * 64;
    for (int v = tid; v < 64 * 12; v += 256) {
        int r = v / 12, c8 = (v % 12) * 8;
        float4 d = {0.f, 0.f, 0.f, 0.f};
        if (n0 + r < NN) d = *(const float4*)(A + (size_t)(n0 + r) * HH + c8);
        *(float4*)(Al + r * LDA1 + c8) = d;
    }
    for (int v = tid; v < 192 * 12; v += 256) {
        int r = v / 12, c8 = (v % 12) * 8;
        *(float4*)(Wl + r * LDA1 + c8) = *(const float4*)(Wt + r * HH + c8);
    }
    if (tid < H2) { red[tid] = 0.f; red[H2 + tid] = 0.f; }
    __syncthreads();
    int wv = tid >> 6, l = tid & 63, lr = l & 15, lg = l >> 4;
    int i0 = wv * 16;
    f32x4 acc[12];
    #pragma unroll
    for (int t = 0; t < 12; ++t) acc[t] = (f32x4){0.f, 0.f, 0.f, 0.f};
    #pragma unroll
    for (int ks = 0; ks < 3; ++ks) {
        int k0 = ks * 32 + lg * 8;
        f16x8 af = *(const f16x8*)(Al + (i0 + lr) * LDA1 + k0);
        #pragma unroll
        for (int t = 0; t < 12; ++t) {
            f16x8 bf = *(const f16x8*)(Wl + (t * 16 + lr) * LDA1 + k0);
            acc[t] = __builtin_amdgcn_mfma_f32_16x16x32_f16(af, bf, acc[t], 0, 0, 0);
        }
    }
    #pragma unroll
    for (int t = 0; t < 12; ++t) {
        int col = t * 16 + lr;
        float s = 0.f, q = 0.f;
        #pragma unroll
        for (int rr = 0; rr < 4; ++rr) {
            int row = n0 + i0 + lg * 4 + rr;
            float v = acc[t][rr];
            if (row < NN) {
                T[(size_t)row * H2 + col] = (f16)v;
                s += v;
                q = fmaf(v, v, q);
            }
        }
        s += __shfl_xor(s, 16); s += __shfl_xor(s, 32);
        q += __shfl_xor(q, 16); q += __shfl_xor(q, 32);
        if (lg == 0) { atomicAdd(&red[col], s); atomicAdd(&red[H2 + col], q); }
    }
    __syncthreads();
    if (tid < H2) {
        atomicAdd(&colsum[tid], red[tid]);
        atomicAdd(&colsumsq[tid], red[H2 + tid]);
    }
}

// ------- gemm2 (MFMA): U = relu(bn1(T)) @ mw2  [N,192]x[192,96], BN fused -------
#define LDA2 200

__global__ __launch_bounds__(256) void gemm2_kernel(const f16* __restrict__ T,
                                                    const f16* __restrict__ Wt,
                                                    const float* __restrict__ cs1,
                                                    const float* __restrict__ cq1,
                                                    const float* __restrict__ g1,
                                                    const float* __restrict__ b1,
                                                    f16* __restrict__ U,
                                                    float* __restrict__ colsum,
                                                    float* __restrict__ colsumsq) {
    __shared__ f16 Al[64 * LDA2];
    __shared__ f16 Wl[96 * LDA2];
    __shared__ float ab[H2 * 2];
    __shared__ float red[HH * 2];
    int tid = threadIdx.x, n0 = blockIdx.x * 64;
    if (tid < H2) {
        const float invN = 1.f / (float)NN;
        float mu = cs1[tid] * invN;
        float var = fmaxf(cq1[tid] * invN - mu * mu, 0.f);
        float a = g1[tid] * rsqrtf(var + EPS_BN);
        ab[tid] = a;
        ab[H2 + tid] = b1[tid] - mu * a;
    }
    if (tid < HH) { red[tid] = 0.f; red[HH + tid] = 0.f; }
    __syncthreads();
    for (int v = tid; v < 64 * 24; v += 256) {
        int r = v / 24, c8 = (v % 24) * 8;
        float4 dd = {0.f, 0.f, 0.f, 0.f};
        if (n0 + r < NN) {
            union { float4 f; f16x2 h[4]; } u, o;
            u.f = *(const float4*)(T + (size_t)(n0 + r) * H2 + c8);
            #pragma unroll
            for (int p = 0; p < 4; ++p) {
                float x0 = fmaxf(fmaf((float)u.h[p].x, ab[c8 + 2 * p], ab[H2 + c8 + 2 * p]), 0.f);
                float x1 = fmaxf(fmaf((float)u.h[p].y, ab[c8 + 2 * p + 1], ab[H2 + c8 + 2 * p + 1]), 0.f);
                o.h[p] = f16x2{(f16)x0, (f16)x1};
            }
            dd = o.f;
        }
        *(float4*)(Al + r * LDA2 + c8) = dd;
    }
    for (int v = tid; v < 96 * 24; v += 256) {
        int r = v / 24, c8 = (v % 24) * 8;
        *(float4*)(Wl + r * LDA2 + c8) = *(const float4*)(Wt + r * H2 + c8);
    }
    __syncthreads();
    int wv = tid >> 6, l = tid & 63, lr = l & 15, lg = l >> 4;
    int i0 = wv * 16;
    f32x4 acc[6];
    #pragma unroll
    for (int t = 0; t < 6; ++t) acc[t] = (f32x4){0.f, 0.f, 0.f, 0.f};
    #pragma unroll
    for (int ks = 0; ks < 6; ++ks) {
        int k0 = ks * 32 + lg * 8;
        f16x8 af = *(const f16x8*)(Al + (i0 + lr) * LDA2 + k0);
        #pragma unroll
        for (int t = 0; t < 6; ++t) {
            f16x8 bf = *(const f16x8*)(Wl + (t * 16 + lr) * LDA2 + k0);
            acc[t] = __builtin_amdgcn_mfma_f32_16x16x32_f16(af, bf, acc[t], 0, 0, 0);
        }
    }
    #pragma unroll
    for (int t = 0; t < 6; ++t) {
        int col = t * 16 + lr;
        float s = 0.f, q = 0.f;
        #pragma unroll
        for (int rr = 0; rr < 4; ++rr) {
            int row = n0 + i0 + lg * 4 + rr;
            float v = acc[t][rr];
            if (row < NN) {
                U[(size_t)row * HH + col] = (f16)v;
                s += v;
                q = fmaf(v, v, q);
            }
        }
        s += __shfl_xor(s, 16); s += __shfl_xor(s, 32);
        q += __shfl_xor(q, 16); q += __shfl_xor(q, 32);
        if (lg == 0) { atomicAdd(&red[col], s); atomicAdd(&red[HH + col], q); }
    }
    __syncthreads();
    if (tid < HH) {
        atomicAdd(&colsum[tid], red[tid]);
        atomicAdd(&colsumsq[tid], red[HH + tid]);
    }
}

// ---------------- h = relu(bn_out(u)), BN finalize fused ----------------

__global__ __launch_bounds__(256) void elem_kernel(const f16* __restrict__ U,
                                                   const float* __restrict__ cs2,
                                                   const float* __restrict__ cq2,
                                                   const float* __restrict__ g2,
                                                   const float* __restrict__ b2,
                                                   f16* __restrict__ Hout) {
    __shared__ float ab[HH * 2];
    int tid = threadIdx.x;
    if (tid < HH) {
        const float invN = 1.f / (float)NN;
        float mu = cs2[tid] * invN;
        float var = fmaxf(cq2[tid] * invN - mu * mu, 0.f);
        float a = g2[tid] * rsqrtf(var + EPS_BN);
        ab[tid] = a;
        ab[HH + tid] = b2[tid] - mu * a;
    }
    __syncthreads();
    int i = blockIdx.x * 256 + tid;
    if (i >= NN * HH / 8) return;
    union { float4 f; f16x2 h[4]; } u, o;
    u.f = ((const float4*)U)[i];
    int k = (i % 12) * 8;
    #pragma unroll
    for (int p = 0; p < 4; ++p) {
        float x0 = fmaxf(fmaf((float)u.h[p].x, ab[k + 2 * p], ab[HH + k + 2 * p]), 0.f);
        float x1 = fmaxf(fmaf((float)u.h[p].y, ab[k + 2 * p + 1], ab[HH + k + 2 * p + 1]), 0.f);
        o.h[p] = f16x2{(f16)x0, (f16)x1};
    }
    ((float4*)Hout)[i] = o.f;
}

// ---------------- mean-pool: segmented register accumulation ----------------

__global__ __launch_bounds__(192) void pool_kernel(const f16* __restrict__ Hfin,
                                                   const int* __restrict__ batch,
                                                   float* __restrict__ pool) {
    int n0 = blockIdx.x * NPB;
    int n1 = (n0 + NPB < NN) ? n0 + NPB : NN;
    int c = threadIdx.x % HH;
    int h = threadIdx.x / HH;
    float acc = 0.f;
    int gcur = -1;
    for (int n = n0 + h; n < n1; n += 2) {
        int g = batch[n];
        if (g != gcur) {
            if (gcur >= 0) atomicAdd(&pool[gcur * HH + c], acc);
            acc = 0.f;
            gcur = g;
        }
        acc += (float)Hfin[(size_t)n * HH + c];
    }
    if (gcur >= 0) atomicAdd(&pool[gcur * HH + c], acc);
}

// final linear; per-graph count via binary search (fused, uniform per block)
__global__ __launch_bounds__(128) void out_kernel(const float* __restrict__ pool,
                                                  const int* __restrict__ batch,
                                                  const float* __restrict__ lw,
                                                  const float* __restrict__ lb,
                                                  float* __restrict__ out) {
    int g = blockIdx.x, o = threadIdx.x;
    int lo = 0, hi = NN;
    while (lo < hi) { int mid = (lo + hi) >> 1; if (batch[mid] < g) lo = mid + 1; else hi = mid; }
    int s = lo;
    lo = 0; hi = NN;
    while (lo < hi) { int mid = (lo + hi) >> 1; if (batch[mid] < g + 1) lo = mid + 1; else hi = mid; }
    float inv = 1.f / fmaxf((float)(lo - s), 1.f);
    float acc = lb[o];
    for (int c = 0; c < HH; ++c) acc = fmaf(pool[g * HH + c] * inv, lw[c * OUTF + o], acc);
    out[(size_t)g * OUTF + o] = acc;
}

// ---------------- host ----------------

extern "C" void kernel_launch(void* const* d_in, const int* in_sizes, int n_in,
                              void* d_out, int out_size, void* d_ws, size_t ws_size,
                              hipStream_t stream) {
    const float* x = (const float*)d_in[0];
    const float* eattr = (const float*)d_in[1];
    const int* eidx = (const int*)d_in[2];
    const int* batch = (const int*)d_in[3];
    const float* w_src1 = (const float*)d_in[4];
    const float* w_dst1 = (const float*)d_in[5];
    const float* w_e[3] = {(const float*)d_in[6], (const float*)d_in[13], (const float*)d_in[20]};
    const float* mw1[3] = {(const float*)d_in[7], (const float*)d_in[14], (const float*)d_in[21]};
    const float* mg[3] = {(const float*)d_in[8], (const float*)d_in[15], (const float*)d_in[22]};
    const float* mb[3] = {(const float*)d_in[9], (const float*)d_in[16], (const float*)d_in[23]};
    const float* mw2[3] = {(const float*)d_in[10], (const float*)d_in[17], (const float*)d_in[24]};
    const float* bng[3] = {(const float*)d_in[11], (const float*)d_in[18], (const float*)d_in[25]};
    const float* bnb[3] = {(const float*)d_in[12], (const float*)d_in[19], (const float*)d_in[26]};
    const float* lin_w = (const float*)d_in[27];
    const float* lin_b = (const float*)d_in[28];
    float* out = (float*)d_out;

    const int* src = eidx;
    const int* dst = eidx + EE;

    // ---- workspace layout ----
    char* base = (char*)d_ws;
    size_t off = 0;
    int* deg = (int*)(base + off); off = align256(off + (size_t)NN * 4);
    int* cnt2 = (int*)(base + off); off = align256(off + (size_t)NN * 4);
    int* offs = (int*)(base + off); off = align256(off + (size_t)(NN + 1) * 4);
    int* bsum = (int*)(base + off); off = align256(off + (size_t)NB_SCAN * 4);
    int* csr_src = (int*)(base + off); off = align256(off + (size_t)EE * 4);
    float* stats = (float*)(base + off); off = align256(off + 576 * 4);
    float* colsum1 = stats;            // 192
    float* colsumsq1 = stats + 192;    // 192
    float* colsum2 = stats + 384;      // 96
    float* colsumsq2 = stats + 480;    // 96
    float* pool = (float*)(base + off); off = align256(off + (size_t)GG * HH * 4);
    f16* wte = (f16*)(base + off); off = align256(off + (size_t)3 * 1536 * 2);
    f16* wt1 = (f16*)(base + off); off = align256(off + (size_t)3 * 18432 * 2);
    f16* wt2 = (f16*)(base + off); off = align256(off + (size_t)3 * 18432 * 2);
    f16* XS = (f16*)(base + off); off = align256(off + (size_t)NN * HH * 2);   // xs -> h
    f16* XD = (f16*)(base + off); off = align256(off + (size_t)NN * HH * 2);   // xd (layer1)
    f16* HP = (f16*)(base + off); off = align256(off + (size_t)NN * HH * 2);   // hpre -> U
    f16* T = (f16*)(base + off); off = align256(off + (size_t)NN * H2 * 2);
    float4* csrea = (float4*)(base + off); off = align256(off + (size_t)EE * 32);
    (void)in_sizes; (void)n_in; (void)out_size; (void)ws_size;

    // ---- CSR build ----
    hipMemsetAsync(deg, 0, (size_t)NN * 4, stream);
    hipMemsetAsync(cnt2, 0, (size_t)NN * 4, stream);
    hist_kernel<<<(EE + 255) / 256, 256, 0, stream>>>(dst, deg);
    scan1_kernel<<<NB_SCAN, 1024, 0, stream>>>(deg, offs, bsum);
    scan2_kernel<<<1, 64, 0, stream>>>(bsum);
    scan3_kernel<<<(NN + 255) / 256, 256, 0, stream>>>(offs, bsum);
    scatter_kernel<<<(EE + 255) / 256, 256, 0, stream>>>(src, dst, offs, cnt2, eattr,
                                                         csr_src, csrea);
    wprep_kernel<<<(4608 + 6 * 18432 + 255) / 256, 256, 0, stream>>>(
        w_e[0], w_e[1], w_e[2], mw1[0], mw1[1], mw1[2], mw2[0], mw2[1], mw2[2],
        wte, wt1, wt2);

    // ---- layer-1 projections ----
    proj_kernel<<<(NN * HH + 255) / 256, 256, 0, stream>>>(x, w_src1, w_dst1, XS, XD);

    // ---- 3 GENConv layers ----
    for (int l = 0; l < 3; ++l) {
        const f16* xdst = (l == 0) ? XD : XS;
        hipMemsetAsync(stats, 0, 576 * 4, stream);
        agg_kernel<<<(NN + 7) / 8, 192, 0, stream>>>(XS, xdst, csrea, wte + l * 1536, offs,
                                                     csr_src, HP);
        gemm1_kernel<<<(NN + 63) / 64, 256, 0, stream>>>(HP, wt1 + l * 18432, T,
                                                         colsum1, colsumsq1);
        gemm2_kernel<<<(NN + 63) / 64, 256, 0, stream>>>(T, wt2 + l * 18432, colsum1,
                                                         colsumsq1, mg[l], mb[l], HP,
                                                         colsum2, colsumsq2);
        elem_kernel<<<(NN * HH / 8 + 255) / 256, 256, 0, stream>>>(HP, colsum2, colsumsq2,
                                                                   bng[l], bnb[l], XS);
    }

    // ---- pooling + final linear ----
    hipMemsetAsync(pool, 0, (size_t)(GG * HH) * 4, stream);
    pool_kernel<<<(NN + NPB - 1) / NPB, 192, 0, stream>>>(XS, batch, pool);
    out_kernel<<<GG, 128, 0, stream>>>(pool, batch, lin_w, lin_b, out);
}